// Round 12
// baseline (351.232 us; speedup 1.0000x reference)
//
#include <hip/hip_runtime.h>

typedef unsigned short u16;
typedef __attribute__((ext_vector_type(8))) short s16x8;      // raw 16B staging
typedef __attribute__((ext_vector_type(8))) _Float16 f16x8;   // MFMA fragments
typedef __attribute__((ext_vector_type(4))) _Float16 f16x4;
typedef __attribute__((ext_vector_type(2))) __fp16 fp16x2;    // cvt_pkrtz return type
typedef __attribute__((ext_vector_type(4))) float f32x4;

#define ASYNC16(gp, lp) \
  __builtin_amdgcn_global_load_lds((__attribute__((address_space(1))) void*)(gp), \
                                   (__attribute__((address_space(3))) void*)(lp), 16, 0, 0)

// ds_read_b64_tr_b16: group of 16 lanes reads a contiguous 4x16 u16 tile
// (per-lane addr = tile_base + l16*8 bytes); lane l16 receives column l16
// (rows j=0..3). offset:N is additive bytes.
#define TR16(dst, p, OFF) \
  asm volatile("ds_read_b64_tr_b16 %0, %1 offset:" #OFF \
               : "=v"(dst) : "v"((__attribute__((address_space(3))) const u16*)(p)))

__device__ __forceinline__ u16 f2h(float f) {
  _Float16 h = (_Float16)f;
  union { _Float16 h; u16 u; } v; v.h = h;
  return v.u;
}
__device__ __forceinline__ float h2f(u16 s) {
  union { _Float16 h; u16 u; } v; v.u = s; return (float)v.h;
}

__device__ __forceinline__ int swz4(int row) { return (row & 3) ^ ((row >> 2) & 3); }

__device__ __forceinline__ unsigned pkrtz_u32(float lo, float hi) {
  union { fp16x2 h; unsigned u; } v;
  v.h = __builtin_amdgcn_cvt_pkrtz(lo, hi);
  return v.u;
}

// ---------------------------------------------------------------------------
// prep: cast trg/src fp32->fp16; transpose+cast weights into Wt[n][k] fp16.
// (verified round 4)
// ---------------------------------------------------------------------------
__global__ __launch_bounds__(256) void prep_kernel(
    const float* __restrict__ trg, const float* __restrict__ src,
    const float* __restrict__ Wsa, const float* __restrict__ Wea,
    u16* __restrict__ trg_h, u16* __restrict__ src_h, u16* __restrict__ wt)
{
  int blk = blockIdx.x, tid = threadIdx.x;
  if (blk < 8192) {
    const float* sp = (blk < 4096) ? trg : src;
    u16* dp = (blk < 4096) ? trg_h : src_h;
    size_t base = ((size_t)(blk & 4095) * 256 + tid) * 8;
    float4 a = *(const float4*)(sp + base);
    float4 c = *(const float4*)(sp + base + 4);
    s16x8 o;
    o[0] = (short)f2h(a.x); o[1] = (short)f2h(a.y);
    o[2] = (short)f2h(a.z); o[3] = (short)f2h(a.w);
    o[4] = (short)f2h(c.x); o[5] = (short)f2h(c.y);
    o[6] = (short)f2h(c.z); o[7] = (short)f2h(c.w);
    *(s16x8*)(dp + base) = o;
  } else {
    int t = (blk - 8192) * 256 + tid;       // < 524288
    int row = t >> 8, k = t & 255;
    const float* W; int sel, col;
    if (row < 768)       { W = Wsa; sel = row >> 8;              col = row & 255; }
    else if (row < 1024) { W = Wsa; sel = 3;                     col = row & 255; }
    else if (row < 1280) { W = Wea; sel = 0;                     col = row & 255; }
    else if (row < 1792) { W = Wea; sel = ((row - 1280) >> 8) + 1; col = (row - 1280) & 255; }
    else                 { W = Wea; sel = 3;                     col = row & 255; }
    wt[(size_t)row * 256 + k] = f2h(W[sel * 65536 + k * 256 + col]);
  }
}

// ---------------------------------------------------------------------------
// fp16 MFMA GEMM: C[M][N] = A[M][256] @ Bt[N][256]^T + bias.
// Round 14: BK 32 -> 64. The 2-barrier-per-K-step structure pays a full
// vmcnt(0)+lgkmcnt(0) drain at each step (m97 analysis: ~20% stall);
// halving steps 8 -> 4 halves that cost. LDS 2x16KB -> 2x32KB (96KB/CU at
// 3 blocks/CU, fits). Swizzle generalized to 8 slots: kc = slot^(row&7),
// inverse applied on the global source (both-sides-or-neither, rule 21).
// Accumulation order over k unchanged -> bit-exact same C as BK=32.
// ---------------------------------------------------------------------------
__global__ __launch_bounds__(256, 3) void gemm_bias_f16(
    const u16* __restrict__ A, const u16* __restrict__ Bt,
    const float* __restrict__ bias, u16* __restrict__ C, int N)
{
  __shared__ u16 Asm[128 * 64];
  __shared__ u16 Bsm[128 * 64];
  const int tid = threadIdx.x;
  const int wv = tid >> 6, ln = tid & 63;
  const int quad = ln >> 4, l16 = ln & 15;
  const int nblk = blockIdx.x;
  const size_t arow0 = (size_t)blockIdx.y * 128;
  const size_t brow0 = (size_t)nblk * 128;
  const int wr = wv >> 1, wc = wv & 1;
  f32x4 acc[4][4];
  const f32x4 VZERO = {0.f, 0.f, 0.f, 0.f};
#pragma unroll
  for (int i = 0; i < 4; ++i)
#pragma unroll
    for (int j = 0; j < 4; ++j) acc[i][j] = VZERO;

  for (int k0 = 0; k0 < 256; k0 += 64) {
    __syncthreads();
#pragma unroll
    for (int j = 0; j < 4; ++j) {
      int c = (j * 4 + wv) * 64 + ln;      // 0..1023, lane-contiguous per wave
      int row = c >> 3, slot = c & 7;
      int kc = slot ^ (row & 7);           // inverse-swizzled global col group
      ASYNC16(A + (arow0 + row) * 256 + k0 + kc * 8, Asm + c * 8);
      ASYNC16(Bt + (brow0 + row) * 256 + k0 + kc * 8, Bsm + c * 8);
    }
    __syncthreads();
#pragma unroll
    for (int kk = 0; kk < 2; ++kk) {
      f16x8 af[4], bfr[4];
#pragma unroll
      for (int mt = 0; mt < 4; ++mt) {
        int tr = wr * 64 + mt * 16 + l16;
        int s = (kk * 4 + quad) ^ (tr & 7);
        af[mt] = *(const f16x8*)(Asm + tr * 64 + s * 8);
      }
#pragma unroll
      for (int nt = 0; nt < 4; ++nt) {
        int tr = wc * 64 + nt * 16 + l16;
        int s = (kk * 4 + quad) ^ (tr & 7);
        bfr[nt] = *(const f16x8*)(Bsm + tr * 64 + s * 8);
      }
#pragma unroll
      for (int mt = 0; mt < 4; ++mt)
#pragma unroll
        for (int nt = 0; nt < 4; ++nt)
          acc[mt][nt] = __builtin_amdgcn_mfma_f32_16x16x32_f16(af[mt], bfr[nt], acc[mt][nt], 0, 0, 0);
    }
  }
#pragma unroll
  for (int nt = 0; nt < 4; ++nt) {
    int col = nblk * 128 + wc * 64 + nt * 16 + l16;
    float bz = bias[col];
#pragma unroll
    for (int mt = 0; mt < 4; ++mt) {
      size_t row0 = arow0 + wr * 64 + mt * 16 + quad * 4;
#pragma unroll
      for (int r = 0; r < 4; ++r)
        C[(row0 + r) * (size_t)N + col] = f2h(acc[mt][nt][r] + bz);
    }
  }
}

// ---------------------------------------------------------------------------
// MFMA attention, no-max softmax — EXACT verified r11 (328.9us total).
// r12's T14 reg-split regressed (+8us: +32 live VGPRs across kt loop);
// r13's T5 setprio alone was noise (+1.4us) -> both reverted.
// V in [key/4][d/16][4][16] subtiles (1 ds_write_b128 per item) +
// ds_read_b64_tr_b16 transpose reads; cvt_pkrtz P pack; rule-18 fence.
// ---------------------------------------------------------------------------
__global__ __launch_bounds__(256, 4) void attn_mfma(
    const u16* __restrict__ Qp, int ldq,
    const u16* __restrict__ Kp, int ldk,
    const u16* __restrict__ Vp, int ldv,
    u16* __restrict__ Op)
{
  __shared__ u16 Ks[256 * 40];
  __shared__ u16 Vs[8192];   // [key/4][d/16][key&3][d&15] subtiled, per kb
  const int tid = threadIdx.x;
  const int wv = tid >> 6, ln = tid & 63;
  const int quad = ln >> 4, l16 = ln & 15;
  const int lin = blockIdx.x;
  const int qb = (lin >> 3) & 3;
  const int g = ((lin >> 5) << 3) | (lin & 7);   // 0..511, partners share XCD
  const int h = g & 7;
  const size_t rb = (size_t)(g >> 3) * 512;
  const f32x4 VZERO = {0.f, 0.f, 0.f, 0.f};

  f16x8 qf[2];
  const _Float16 qs = (_Float16)0.25503492f;    // (1/sqrt(32)) * log2(e)
#pragma unroll
  for (int mq = 0; mq < 2; ++mq) {
    int qrow = qb * 128 + wv * 32 + mq * 16 + l16;
    qf[mq] = *(const f16x8*)(Qp + (rb + qrow) * (size_t)ldq + h * 32 + quad * 8);
#pragma unroll
    for (int j = 0; j < 8; ++j) qf[mq][j] *= qs;
  }
  f16x8 onesf;
#pragma unroll
  for (int j = 0; j < 8; ++j) onesf[j] = (_Float16)1.0f;

  f32x4 o[2][2], osum[2];
#pragma unroll
  for (int mq = 0; mq < 2; ++mq) { o[mq][0] = VZERO; o[mq][1] = VZERO; osum[mq] = VZERO; }

  for (int kb = 0; kb < 2; ++kb) {
    __syncthreads();
    for (int c = tid; c < 1024; c += 256) {
      int row = c >> 2, part = c & 3;
      s16x8 kv = *(const s16x8*)(Kp + (rb + kb * 256 + row) * (size_t)ldk + h * 32 + part * 8);
      *(s16x8*)(Ks + row * 40 + part * 8) = kv;
      s16x8 vv = *(const s16x8*)(Vp + (rb + kb * 256 + row) * (size_t)ldv + h * 32 + part * 8);
      // subtiled: elem = (key>>2)*128 + (d>>4)*64 + (key&3)*16 + (d&15)
      *(s16x8*)(Vs + (row >> 2) * 128 + (part >> 1) * 64 + (row & 3) * 16 + (part & 1) * 8) = vv;
    }
    __syncthreads();
    for (int kt = 0; kt < 8; ++kt) {
      f16x8 kf0 = *(const f16x8*)(Ks + (kt * 32 + l16) * 40 + quad * 8);
      f16x8 kf1 = *(const f16x8*)(Ks + (kt * 32 + 16 + l16) * 40 + quad * 8);
      // V transpose reads: tile base = subtile (kq = kt*8+quad*2, dg=0)
      const u16* vb = Vs + (kt * 8 + quad * 2) * 128 + l16 * 4;
      f16x4 v00, v01, v10, v11;
      TR16(v00, vb, 0);     // keys quad*8+0..3, d = l16
      TR16(v01, vb, 256);   // keys quad*8+4..7, d = l16
      TR16(v10, vb, 128);   // keys quad*8+0..3, d = 16+l16
      TR16(v11, vb, 384);   // keys quad*8+4..7, d = 16+l16
      f16x8 pf[2];
#pragma unroll
      for (int mq = 0; mq < 2; ++mq) {
        // swapped: A=K rows -> D[key][q]; lane holds q=l16, keys quad*4+r
        f32x4 s0 = __builtin_amdgcn_mfma_f32_16x16x32_f16(kf0, qf[mq], VZERO, 0, 0, 0);
        f32x4 s1 = __builtin_amdgcn_mfma_f32_16x16x32_f16(kf1, qf[mq], VZERO, 0, 0, 0);
        // exp + packed RTZ f16 convert: u0=keys 4q+{0,1}, u1=4q+{2,3},
        //                               u2=16+4q+{0,1}, u3=16+4q+{2,3}
        unsigned u0 = pkrtz_u32(__builtin_amdgcn_exp2f(s0[0]),
                                __builtin_amdgcn_exp2f(s0[1]));
        unsigned u1 = pkrtz_u32(__builtin_amdgcn_exp2f(s0[2]),
                                __builtin_amdgcn_exp2f(s0[3]));
        unsigned u2 = pkrtz_u32(__builtin_amdgcn_exp2f(s1[0]),
                                __builtin_amdgcn_exp2f(s1[1]));
        unsigned u3 = pkrtz_u32(__builtin_amdgcn_exp2f(s1[2]),
                                __builtin_amdgcn_exp2f(s1[3]));
        // in-register P rearrange to A-fragment (keys 8*quad..8*quad+7)
        asm("v_permlane32_swap_b32 %0, %1" : "+v"(u0), "+v"(u2));
        asm("v_permlane32_swap_b32 %0, %1" : "+v"(u1), "+v"(u3));
        asm("v_permlane16_swap_b32 %0, %1" : "+v"(u0), "+v"(u2));
        asm("v_permlane16_swap_b32 %0, %1" : "+v"(u1), "+v"(u3));
        union { unsigned u[4]; f16x8 f; } P;
        P.u[0] = u0; P.u[1] = u1; P.u[2] = u2; P.u[3] = u3;
        pf[mq] = P.f;
      }
      // drain the asm tr-reads (and anything else) before PV consumes them;
      // sched_barrier stops MFMA hoisting past the inline waitcnt (rule 18)
      asm volatile("s_waitcnt lgkmcnt(0)" ::: "memory");
      __builtin_amdgcn_sched_barrier(0);
      f16x8 vf0 = __builtin_shufflevector(v00, v01, 0, 1, 2, 3, 4, 5, 6, 7);
      f16x8 vf1 = __builtin_shufflevector(v10, v11, 0, 1, 2, 3, 4, 5, 6, 7);
#pragma unroll
      for (int mq = 0; mq < 2; ++mq) {
        o[mq][0] = __builtin_amdgcn_mfma_f32_16x16x32_f16(pf[mq], vf0, o[mq][0], 0, 0, 0);
        o[mq][1] = __builtin_amdgcn_mfma_f32_16x16x32_f16(pf[mq], vf1, o[mq][1], 0, 0, 0);
        osum[mq] = __builtin_amdgcn_mfma_f32_16x16x32_f16(pf[mq], onesf, osum[mq], 0, 0, 0);
      }
    }
  }
#pragma unroll
  for (int mq = 0; mq < 2; ++mq)
#pragma unroll
    for (int r = 0; r < 4; ++r) {
      float inv = 1.f / osum[mq][r];
      size_t row = rb + qb * 128 + wv * 32 + mq * 16 + quad * 4 + r;
      Op[row * 256 + h * 32 + l16]      = f2h(o[mq][0][r] * inv);
      Op[row * 256 + h * 32 + 16 + l16] = f2h(o[mq][1][r] * inv);
    }
}

// ---------------------------------------------------------------------------
// O-projection (MFMA) + bias + fp16 residual + LayerNorm -> fp16 h (+norms).
// (verified round 9)
// ---------------------------------------------------------------------------
__global__ __launch_bounds__(256, 3) void lnproj_kernel(
    const u16* __restrict__ A, const u16* __restrict__ Wt,
    const float* __restrict__ bo, const u16* __restrict__ resid,
    const float* __restrict__ g, const float* __restrict__ lb,
    u16* __restrict__ Hh, float* __restrict__ norms)
{
  __shared__ u16 Asm[64 * 32];
  __shared__ u16 Bsm[256 * 32];
  const int tid = threadIdx.x;
  const int wv = tid >> 6, ln = tid & 63;
  const int quad = ln >> 4, l16 = ln & 15;
  const size_t arow0 = (size_t)blockIdx.x * 64;
  f32x4 acc[16];
  const f32x4 VZERO = {0.f, 0.f, 0.f, 0.f};
#pragma unroll
  for (int nt = 0; nt < 16; ++nt) acc[nt] = VZERO;

  for (int k0 = 0; k0 < 256; k0 += 32) {
    __syncthreads();
    {
      int c = tid;
      int row = c >> 2, slot = c & 3;
      int kc = slot ^ swz4(row);
      ASYNC16(A + (arow0 + row) * 256 + k0 + kc * 8, Asm + c * 8);
    }
#pragma unroll
    for (int j = 0; j < 4; ++j) {
      int c = (j * 4 + wv) * 64 + ln;
      int row = c >> 2, slot = c & 3;
      int kc = slot ^ swz4(row);
      ASYNC16(Wt + (size_t)row * 256 + k0 + kc * 8, Bsm + c * 8);
    }
    __syncthreads();
    int tr = wv * 16 + l16;
    int aslot = quad ^ swz4(tr);
    f16x8 af = *(const f16x8*)(Asm + (tr * 4 + aslot) * 8);
#pragma unroll
    for (int nt = 0; nt < 16; ++nt) {
      int br = nt * 16 + l16;
      int bslot = quad ^ swz4(br);
      f16x8 bfr = *(const f16x8*)(Bsm + (br * 4 + bslot) * 8);
      acc[nt] = __builtin_amdgcn_mfma_f32_16x16x32_f16(af, bfr, acc[nt], 0, 0, 0);
    }
  }
  float gv[16], bv[16], bov[16];
#pragma unroll
  for (int nt = 0; nt < 16; ++nt) {
    int col = nt * 16 + l16;
    gv[nt] = g[col]; bv[nt] = lb[col]; bov[nt] = bo[col];
  }
#pragma unroll
  for (int r = 0; r < 4; ++r) {
    size_t row = arow0 + wv * 16 + quad * 4 + r;
    const u16* rrow = resid + row * 256;
    float vals[16]; float s = 0.f;
#pragma unroll
    for (int nt = 0; nt < 16; ++nt) {
      float v = acc[nt][r] + bov[nt] + h2f(rrow[nt * 16 + l16]);
      vals[nt] = v; s += v;
    }
#pragma unroll
    for (int m = 1; m < 16; m <<= 1) s += __shfl_xor(s, m);
    float mean = s * (1.f / 256.f);
    float sq = 0.f;
#pragma unroll
    for (int nt = 0; nt < 16; ++nt) { float d = vals[nt] - mean; sq = fmaf(d, d, sq); }
#pragma unroll
    for (int m = 1; m < 16; m <<= 1) sq += __shfl_xor(sq, m);
    float rstd = rsqrtf(sq * (1.f / 256.f) + 1e-5f);
    float ssq = 0.f;
#pragma unroll
    for (int nt = 0; nt < 16; ++nt) {
      float hv = (vals[nt] - mean) * rstd * gv[nt] + bv[nt];
      Hh[row * 256 + nt * 16 + l16] = f2h(hv);
      ssq = fmaf(hv, hv, ssq);
    }
    if (norms) {
#pragma unroll
      for (int m = 1; m < 16; m <<= 1) ssq += __shfl_xor(ssq, m);
      if (l16 == 0) norms[row] = sqrtf(ssq);
    }
  }
}

// ---------------------------------------------------------------------------
// Pooling softmax (verified) — normalizes w in-place, zeroes pooled.
// ---------------------------------------------------------------------------
__global__ __launch_bounds__(256) void softmax_kernel(const float* norms, float* w,
                                                      float* __restrict__ pooled)
{
  int b = blockIdx.x, tid = threadIdx.x;
  int ln = tid & 63, wvi = tid >> 6;
  __shared__ float red[8];
  const float* nb = norms + b * 512;
  float n0 = nb[tid], n1 = nb[tid + 256];
  float mx = fmaxf(n0, n1);
#pragma unroll
  for (int m = 1; m < 64; m <<= 1) mx = fmaxf(mx, __shfl_xor(mx, m));
  if (ln == 0) red[wvi] = mx;
  __syncthreads();
  mx = fmaxf(fmaxf(red[0], red[1]), fmaxf(red[2], red[3]));
  float e0 = __expf(n0 - mx), e1 = __expf(n1 - mx);
  float s = e0 + e1;
#pragma unroll
  for (int m = 1; m < 64; m <<= 1) s += __shfl_xor(s, m);
  if (ln == 0) red[4 + wvi] = s;
  __syncthreads();
  s = red[4] + red[5] + red[6] + red[7];
  float inv = 1.f / s;
  w[b * 512 + tid] = e0 * inv;
  w[b * 512 + tid + 256] = e1 * inv;
  pooled[b * 256 + tid] = 0.f;
}

__global__ __launch_bounds__(256) void poolsum_kernel(const float* __restrict__ w,
                                                      const u16* __restrict__ h,
                                                      float* __restrict__ pooled)
{
  int b = blockIdx.x, sl = blockIdx.y, d = threadIdx.x;
  const u16* hb = h + ((size_t)b * 512 + sl * 64) * 256 + d;
  const float* wb = w + b * 512 + sl * 64;
  float acc = 0.f;
#pragma unroll 8
  for (int a = 0; a < 64; ++a) acc = fmaf(wb[a], h2f(hb[(size_t)a * 256]), acc);
  atomicAdd(&pooled[b * 256 + d], acc);
}

// ---------------------------------------------------------------------------
// FC stack, parallelized (verified round 7): fc1 then fused fc2+out.
// ---------------------------------------------------------------------------
__global__ __launch_bounds__(512) void fc1_kernel(
    const float* __restrict__ pooled, const float* __restrict__ Wfc1,
    const float* __restrict__ bfc1, float* __restrict__ x1)
{
  int b = blockIdx.x, tid = threadIdx.x;
  __shared__ float px[256];
  if (tid < 256) px[tid] = pooled[b * 256 + tid];
  __syncthreads();
  float a = bfc1[tid];
#pragma unroll 8
  for (int d = 0; d < 256; ++d) a = fmaf(px[d], Wfc1[d * 512 + tid], a);
  x1[b * 512 + tid] = fmaxf(a, 0.f);
}

__global__ __launch_bounds__(512) void fc23_kernel(
    const float* __restrict__ x1, const float* __restrict__ Wfc2,
    const float* __restrict__ bfc2, const float* __restrict__ Wout,
    const float* __restrict__ bout, float* __restrict__ out)
{
  int b = blockIdx.x, tid = threadIdx.x;
  __shared__ float sx[512];
  __shared__ float rr[16];
  sx[tid] = x1[b * 512 + tid];
  __syncthreads();
  float a = bfc2[tid];
#pragma unroll 8
  for (int d = 0; d < 512; ++d) a = fmaf(sx[d], Wfc2[d * 512 + tid], a);
  a = fmaxf(a, 0.f);
  float p0 = a * Wout[tid * 2];
  float p1 = a * Wout[tid * 2 + 1];
  int ln = tid & 63, wvi = tid >> 6;
#pragma unroll
  for (int m = 1; m < 64; m <<= 1) { p0 += __shfl_xor(p0, m); p1 += __shfl_xor(p1, m); }
  if (ln == 0) { rr[wvi] = p0; rr[8 + wvi] = p1; }
  __syncthreads();
  if (tid == 0) {
    float s = 0.f;
#pragma unroll
    for (int i = 0; i < 8; ++i) s += rr[i];
    out[b * 2] = s + bout[0];
  }
  if (tid == 1) {
    float s = 0.f;
#pragma unroll
    for (int i = 0; i < 8; ++i) s += rr[8 + i];
    out[b * 2 + 1] = s + bout[1];
  }
}

// ---------------------------------------------------------------------------
extern "C" void kernel_launch(void* const* d_in, const int* in_sizes, int n_in,
                              void* d_out, int out_size, void* d_ws, size_t ws_size,
                              hipStream_t stream) {
  const float* trg  = (const float*)d_in[0];
  const float* src  = (const float*)d_in[1];
  const float* Wsa  = (const float*)d_in[2];
  const float* bsa  = (const float*)d_in[3];
  const float* Wea  = (const float*)d_in[4];
  const float* bea  = (const float*)d_in[5];
  const float* lng  = (const float*)d_in[6];
  const float* lnb  = (const float*)d_in[7];
  const float* Wfc1 = (const float*)d_in[8];
  const float* bfc1 = (const float*)d_in[9];
  const float* Wfc2 = (const float*)d_in[10];
  const float* bfc2 = (const float*)d_in[11];
  const float* Wout = (const float*)d_in[12];
  const float* bout = (const float*)d_in[13];
  float* out = (float*)d_out;

  const size_t M = 32768;  // B*A
  char* ws = (char*)d_ws;
  u16* trg_h = (u16*)ws;                ws += M * 256 * 2;
  u16* src_h = (u16*)ws;                ws += M * 256 * 2;
  u16* wt     = (u16*)ws;               ws += 2048 * 256 * 2;
  u16* qkv    = (u16*)ws;               ws += M * 768 * 2;
  u16* attnb  = (u16*)ws;               ws += M * 256 * 2;
  u16* hh     = (u16*)ws;               ws += M * 256 * 2;
  u16* h2h    = (u16*)ws;               ws += M * 256 * 2;
  float* norms = (float*)ws;            ws += M * 4;
  float* pooled = (float*)ws;           ws += 64 * 256 * 4;
  float* x1buf = (float*)ws;            ws += 64 * 512 * 4;

  u16* wt_sa_qkv = wt;
  u16* wt_sa_o   = wt + 768 * 256;
  u16* wt_ea_q   = wt + 1024 * 256;
  u16* wt_ea_kv  = wt + 1280 * 256;
  u16* wt_ea_o   = wt + 1792 * 256;
  u16* kvb = qkv + M * 256;

  prep_kernel<<<10240, 256, 0, stream>>>(trg, src, Wsa, Wea, trg_h, src_h, wt);
  // self-attention
  gemm_bias_f16<<<dim3(6, 256), 256, 0, stream>>>(trg_h, wt_sa_qkv, bsa, qkv, 768);
  attn_mfma<<<2048, 256, 0, stream>>>(qkv, 768, qkv + 256, 768, qkv + 512, 768, attnb);
  lnproj_kernel<<<512, 256, 0, stream>>>(attnb, wt_sa_o, bsa + 768, trg_h, lng, lnb,
                                         hh, nullptr);
  // cross-attention
  gemm_bias_f16<<<dim3(2, 256), 256, 0, stream>>>(hh, wt_ea_q, bea, qkv, 256);
  gemm_bias_f16<<<dim3(4, 256), 256, 0, stream>>>(src_h, wt_ea_kv, bea + 256, kvb, 512);
  attn_mfma<<<2048, 256, 0, stream>>>(qkv, 256, kvb, 512, kvb + 256, 512, attnb);
  lnproj_kernel<<<512, 256, 0, stream>>>(attnb, wt_ea_o, bea + 768, hh, lng, lnb,
                                         h2h, norms);
  // pooling + FC head
  softmax_kernel<<<64, 256, 0, stream>>>(norms, norms, pooled);
  poolsum_kernel<<<dim3(64, 8), 256, 0, stream>>>(norms, h2h, pooled);
  fc1_kernel<<<64, 512, 0, stream>>>(pooled, Wfc1, bfc1, x1buf);
  fc23_kernel<<<64, 512, 0, stream>>>(x1buf, Wfc2, bfc2, Wout, bout, out);

  (void)in_sizes; (void)n_in; (void)out_size; (void)ws_size;
}

// Round 15
// 319.665 us; speedup vs baseline: 1.0988x; 1.0988x over previous
//
#include <hip/hip_runtime.h>

typedef unsigned short u16;
typedef __attribute__((ext_vector_type(8))) short s16x8;      // raw 16B staging
typedef __attribute__((ext_vector_type(8))) _Float16 f16x8;   // MFMA fragments
typedef __attribute__((ext_vector_type(4))) _Float16 f16x4;
typedef __attribute__((ext_vector_type(2))) __fp16 fp16x2;    // cvt_pkrtz return type
typedef __attribute__((ext_vector_type(4))) float f32x4;

#define ASYNC16(gp, lp) \
  __builtin_amdgcn_global_load_lds((__attribute__((address_space(1))) void*)(gp), \
                                   (__attribute__((address_space(3))) void*)(lp), 16, 0, 0)

// ds_read_b64_tr_b16: group of 16 lanes reads a contiguous 4x16 u16 tile
// (per-lane addr = tile_base + l16*8 bytes); lane l16 receives column l16
// (rows j=0..3). offset:N is additive bytes.
#define TR16(dst, p, OFF) \
  asm volatile("ds_read_b64_tr_b16 %0, %1 offset:" #OFF \
               : "=v"(dst) : "v"((__attribute__((address_space(3))) const u16*)(p)))

__device__ __forceinline__ u16 f2h(float f) {
  _Float16 h = (_Float16)f;
  union { _Float16 h; u16 u; } v; v.h = h;
  return v.u;
}
__device__ __forceinline__ float h2f(u16 s) {
  union { _Float16 h; u16 u; } v; v.u = s; return (float)v.h;
}

__device__ __forceinline__ int swz4(int row) { return (row & 3) ^ ((row >> 2) & 3); }

__device__ __forceinline__ unsigned pkrtz_u32(float lo, float hi) {
  union { fp16x2 h; unsigned u; } v;
  v.h = __builtin_amdgcn_cvt_pkrtz(lo, hi);
  return v.u;
}

// ---------------------------------------------------------------------------
// prep: cast trg/src fp32->fp16; transpose+cast weights into Wt[n][k] fp16;
// round 15: also zeroes pooled (blocks 10240..10303) so the standalone
// softmax kernel (which used to zero it) can be fused into poolsum.
// ---------------------------------------------------------------------------
__global__ __launch_bounds__(256) void prep_kernel(
    const float* __restrict__ trg, const float* __restrict__ src,
    const float* __restrict__ Wsa, const float* __restrict__ Wea,
    u16* __restrict__ trg_h, u16* __restrict__ src_h, u16* __restrict__ wt,
    float* __restrict__ pooled)
{
  int blk = blockIdx.x, tid = threadIdx.x;
  if (blk < 8192) {
    const float* sp = (blk < 4096) ? trg : src;
    u16* dp = (blk < 4096) ? trg_h : src_h;
    size_t base = ((size_t)(blk & 4095) * 256 + tid) * 8;
    float4 a = *(const float4*)(sp + base);
    float4 c = *(const float4*)(sp + base + 4);
    s16x8 o;
    o[0] = (short)f2h(a.x); o[1] = (short)f2h(a.y);
    o[2] = (short)f2h(a.z); o[3] = (short)f2h(a.w);
    o[4] = (short)f2h(c.x); o[5] = (short)f2h(c.y);
    o[6] = (short)f2h(c.z); o[7] = (short)f2h(c.w);
    *(s16x8*)(dp + base) = o;
  } else if (blk < 10240) {
    int t = (blk - 8192) * 256 + tid;       // < 524288
    int row = t >> 8, k = t & 255;
    const float* W; int sel, col;
    if (row < 768)       { W = Wsa; sel = row >> 8;              col = row & 255; }
    else if (row < 1024) { W = Wsa; sel = 3;                     col = row & 255; }
    else if (row < 1280) { W = Wea; sel = 0;                     col = row & 255; }
    else if (row < 1792) { W = Wea; sel = ((row - 1280) >> 8) + 1; col = (row - 1280) & 255; }
    else                 { W = Wea; sel = 3;                     col = row & 255; }
    wt[(size_t)row * 256 + k] = f2h(W[sel * 65536 + k * 256 + col]);
  } else {
    int b = blk - 10240;                    // 0..63
    pooled[b * 256 + tid] = 0.f;
  }
}

// ---------------------------------------------------------------------------
// fp16 MFMA GEMM (verified round 4, BK=32): C = A @ Bt^T + bias.
// r14's BK=64 regressed (351 vs 330): doubled in-flight loads + deeper
// unroll raised pressure; barrier drain was already TLP-hidden. Reverted.
// ---------------------------------------------------------------------------
__global__ __launch_bounds__(256, 3) void gemm_bias_f16(
    const u16* __restrict__ A, const u16* __restrict__ Bt,
    const float* __restrict__ bias, u16* __restrict__ C, int N)
{
  __shared__ u16 Asm[128 * 32];
  __shared__ u16 Bsm[128 * 32];
  const int tid = threadIdx.x;
  const int wv = tid >> 6, ln = tid & 63;
  const int quad = ln >> 4, l16 = ln & 15;
  const int nblk = blockIdx.x;
  const size_t arow0 = (size_t)blockIdx.y * 128;
  const size_t brow0 = (size_t)nblk * 128;
  const int wr = wv >> 1, wc = wv & 1;
  f32x4 acc[4][4];
  const f32x4 VZERO = {0.f, 0.f, 0.f, 0.f};
#pragma unroll
  for (int i = 0; i < 4; ++i)
#pragma unroll
    for (int j = 0; j < 4; ++j) acc[i][j] = VZERO;

  for (int k0 = 0; k0 < 256; k0 += 32) {
    __syncthreads();
#pragma unroll
    for (int j = 0; j < 2; ++j) {
      int c = (j * 4 + wv) * 64 + ln;
      int row = c >> 2, slot = c & 3;
      int kc = slot ^ swz4(row);
      ASYNC16(A + (arow0 + row) * 256 + k0 + kc * 8, Asm + c * 8);
      ASYNC16(Bt + (brow0 + row) * 256 + k0 + kc * 8, Bsm + c * 8);
    }
    __syncthreads();
    f16x8 af[4], bfr[4];
#pragma unroll
    for (int mt = 0; mt < 4; ++mt) {
      int tr = wr * 64 + mt * 16 + l16;
      int slot = quad ^ swz4(tr);
      af[mt] = *(const f16x8*)(Asm + (tr * 4 + slot) * 8);
    }
#pragma unroll
    for (int nt = 0; nt < 4; ++nt) {
      int tr = wc * 64 + nt * 16 + l16;
      int slot = quad ^ swz4(tr);
      bfr[nt] = *(const f16x8*)(Bsm + (tr * 4 + slot) * 8);
    }
#pragma unroll
    for (int mt = 0; mt < 4; ++mt)
#pragma unroll
      for (int nt = 0; nt < 4; ++nt)
        acc[mt][nt] = __builtin_amdgcn_mfma_f32_16x16x32_f16(af[mt], bfr[nt], acc[mt][nt], 0, 0, 0);
  }
#pragma unroll
  for (int nt = 0; nt < 4; ++nt) {
    int col = nblk * 128 + wc * 64 + nt * 16 + l16;
    float bz = bias[col];
#pragma unroll
    for (int mt = 0; mt < 4; ++mt) {
      size_t row0 = arow0 + wr * 64 + mt * 16 + quad * 4;
#pragma unroll
      for (int r = 0; r < 4; ++r)
        C[(row0 + r) * (size_t)N + col] = f2h(acc[mt][nt][r] + bz);
    }
  }
}

// ---------------------------------------------------------------------------
// Round 15: ea_q (N=256, 2 nblks) + ea_kv (N=512, 4 nblks) fused into one
// dispatch (nblk 0-1 -> q config, 2-5 -> kv). Same verified BK=32 body;
// per-block uniform pointer select. Saves one launch + inter-dispatch drain.
// ---------------------------------------------------------------------------
__global__ __launch_bounds__(256, 3) void gemm_ea_kernel(
    const u16* __restrict__ Aq, const u16* __restrict__ Btq,
    const float* __restrict__ biasq, u16* __restrict__ Cq,
    const u16* __restrict__ Akv, const u16* __restrict__ Btkv,
    const float* __restrict__ biaskv, u16* __restrict__ Ckv)
{
  __shared__ u16 Asm[128 * 32];
  __shared__ u16 Bsm[128 * 32];
  const int tid = threadIdx.x;
  const int wv = tid >> 6, ln = tid & 63;
  const int quad = ln >> 4, l16 = ln & 15;
  const bool isq = blockIdx.x < 2;
  const int nb = isq ? blockIdx.x : blockIdx.x - 2;
  const u16* A  = isq ? Aq : Akv;
  const u16* Bt = isq ? Btq : Btkv;
  const float* bias = isq ? biasq : biaskv;
  u16* C = isq ? Cq : Ckv;
  const int N = isq ? 256 : 512;
  const size_t arow0 = (size_t)blockIdx.y * 128;
  const size_t brow0 = (size_t)nb * 128;
  const int wr = wv >> 1, wc = wv & 1;
  f32x4 acc[4][4];
  const f32x4 VZERO = {0.f, 0.f, 0.f, 0.f};
#pragma unroll
  for (int i = 0; i < 4; ++i)
#pragma unroll
    for (int j = 0; j < 4; ++j) acc[i][j] = VZERO;

  for (int k0 = 0; k0 < 256; k0 += 32) {
    __syncthreads();
#pragma unroll
    for (int j = 0; j < 2; ++j) {
      int c = (j * 4 + wv) * 64 + ln;
      int row = c >> 2, slot = c & 3;
      int kc = slot ^ swz4(row);
      ASYNC16(A + (arow0 + row) * 256 + k0 + kc * 8, Asm + c * 8);
      ASYNC16(Bt + (brow0 + row) * 256 + k0 + kc * 8, Bsm + c * 8);
    }
    __syncthreads();
    f16x8 af[4], bfr[4];
#pragma unroll
    for (int mt = 0; mt < 4; ++mt) {
      int tr = wr * 64 + mt * 16 + l16;
      int slot = quad ^ swz4(tr);
      af[mt] = *(const f16x8*)(Asm + (tr * 4 + slot) * 8);
    }
#pragma unroll
    for (int nt = 0; nt < 4; ++nt) {
      int tr = wc * 64 + nt * 16 + l16;
      int slot = quad ^ swz4(tr);
      bfr[nt] = *(const f16x8*)(Bsm + (tr * 4 + slot) * 8);
    }
#pragma unroll
    for (int mt = 0; mt < 4; ++mt)
#pragma unroll
      for (int nt = 0; nt < 4; ++nt)
        acc[mt][nt] = __builtin_amdgcn_mfma_f32_16x16x32_f16(af[mt], bfr[nt], acc[mt][nt], 0, 0, 0);
  }
#pragma unroll
  for (int nt = 0; nt < 4; ++nt) {
    int col = nb * 128 + wc * 64 + nt * 16 + l16;
    float bz = bias[col];
#pragma unroll
    for (int mt = 0; mt < 4; ++mt) {
      size_t row0 = arow0 + wr * 64 + mt * 16 + quad * 4;
#pragma unroll
      for (int r = 0; r < 4; ++r)
        C[(row0 + r) * (size_t)N + col] = f2h(acc[mt][nt][r] + bz);
    }
  }
}

// ---------------------------------------------------------------------------
// MFMA attention, no-max softmax — EXACT verified r11 (328.9us total).
// r12's T14 reg-split regressed (+8us); r13's T5 setprio was noise;
// r14's BK=64 gemm regressed. All reverted to the verified forms.
// V in [key/4][d/16][4][16] subtiles (1 ds_write_b128 per item) +
// ds_read_b64_tr_b16 transpose reads; cvt_pkrtz P pack; rule-18 fence.
// ---------------------------------------------------------------------------
__global__ __launch_bounds__(256, 4) void attn_mfma(
    const u16* __restrict__ Qp, int ldq,
    const u16* __restrict__ Kp, int ldk,
    const u16* __restrict__ Vp, int ldv,
    u16* __restrict__ Op)
{
  __shared__ u16 Ks[256 * 40];
  __shared__ u16 Vs[8192];   // [key/4][d/16][key&3][d&15] subtiled, per kb
  const int tid = threadIdx.x;
  const int wv = tid >> 6, ln = tid & 63;
  const int quad = ln >> 4, l16 = ln & 15;
  const int lin = blockIdx.x;
  const int qb = (lin >> 3) & 3;
  const int g = ((lin >> 5) << 3) | (lin & 7);   // 0..511, partners share XCD
  const int h = g & 7;
  const size_t rb = (size_t)(g >> 3) * 512;
  const f32x4 VZERO = {0.f, 0.f, 0.f, 0.f};

  f16x8 qf[2];
  const _Float16 qs = (_Float16)0.25503492f;    // (1/sqrt(32)) * log2(e)
#pragma unroll
  for (int mq = 0; mq < 2; ++mq) {
    int qrow = qb * 128 + wv * 32 + mq * 16 + l16;
    qf[mq] = *(const f16x8*)(Qp + (rb + qrow) * (size_t)ldq + h * 32 + quad * 8);
#pragma unroll
    for (int j = 0; j < 8; ++j) qf[mq][j] *= qs;
  }
  f16x8 onesf;
#pragma unroll
  for (int j = 0; j < 8; ++j) onesf[j] = (_Float16)1.0f;

  f32x4 o[2][2], osum[2];
#pragma unroll
  for (int mq = 0; mq < 2; ++mq) { o[mq][0] = VZERO; o[mq][1] = VZERO; osum[mq] = VZERO; }

  for (int kb = 0; kb < 2; ++kb) {
    __syncthreads();
    for (int c = tid; c < 1024; c += 256) {
      int row = c >> 2, part = c & 3;
      s16x8 kv = *(const s16x8*)(Kp + (rb + kb * 256 + row) * (size_t)ldk + h * 32 + part * 8);
      *(s16x8*)(Ks + row * 40 + part * 8) = kv;
      s16x8 vv = *(const s16x8*)(Vp + (rb + kb * 256 + row) * (size_t)ldv + h * 32 + part * 8);
      // subtiled: elem = (key>>2)*128 + (d>>4)*64 + (key&3)*16 + (d&15)
      *(s16x8*)(Vs + (row >> 2) * 128 + (part >> 1) * 64 + (row & 3) * 16 + (part & 1) * 8) = vv;
    }
    __syncthreads();
    for (int kt = 0; kt < 8; ++kt) {
      f16x8 kf0 = *(const f16x8*)(Ks + (kt * 32 + l16) * 40 + quad * 8);
      f16x8 kf1 = *(const f16x8*)(Ks + (kt * 32 + 16 + l16) * 40 + quad * 8);
      // V transpose reads: tile base = subtile (kq = kt*8+quad*2, dg=0)
      const u16* vb = Vs + (kt * 8 + quad * 2) * 128 + l16 * 4;
      f16x4 v00, v01, v10, v11;
      TR16(v00, vb, 0);     // keys quad*8+0..3, d = l16
      TR16(v01, vb, 256);   // keys quad*8+4..7, d = l16
      TR16(v10, vb, 128);   // keys quad*8+0..3, d = 16+l16
      TR16(v11, vb, 384);   // keys quad*8+4..7, d = 16+l16
      f16x8 pf[2];
#pragma unroll
      for (int mq = 0; mq < 2; ++mq) {
        // swapped: A=K rows -> D[key][q]; lane holds q=l16, keys quad*4+r
        f32x4 s0 = __builtin_amdgcn_mfma_f32_16x16x32_f16(kf0, qf[mq], VZERO, 0, 0, 0);
        f32x4 s1 = __builtin_amdgcn_mfma_f32_16x16x32_f16(kf1, qf[mq], VZERO, 0, 0, 0);
        // exp + packed RTZ f16 convert: u0=keys 4q+{0,1}, u1=4q+{2,3},
        //                               u2=16+4q+{0,1}, u3=16+4q+{2,3}
        unsigned u0 = pkrtz_u32(__builtin_amdgcn_exp2f(s0[0]),
                                __builtin_amdgcn_exp2f(s0[1]));
        unsigned u1 = pkrtz_u32(__builtin_amdgcn_exp2f(s0[2]),
                                __builtin_amdgcn_exp2f(s0[3]));
        unsigned u2 = pkrtz_u32(__builtin_amdgcn_exp2f(s1[0]),
                                __builtin_amdgcn_exp2f(s1[1]));
        unsigned u3 = pkrtz_u32(__builtin_amdgcn_exp2f(s1[2]),
                                __builtin_amdgcn_exp2f(s1[3]));
        // in-register P rearrange to A-fragment (keys 8*quad..8*quad+7)
        asm("v_permlane32_swap_b32 %0, %1" : "+v"(u0), "+v"(u2));
        asm("v_permlane32_swap_b32 %0, %1" : "+v"(u1), "+v"(u3));
        asm("v_permlane16_swap_b32 %0, %1" : "+v"(u0), "+v"(u2));
        asm("v_permlane16_swap_b32 %0, %1" : "+v"(u1), "+v"(u3));
        union { unsigned u[4]; f16x8 f; } P;
        P.u[0] = u0; P.u[1] = u1; P.u[2] = u2; P.u[3] = u3;
        pf[mq] = P.f;
      }
      // drain the asm tr-reads (and anything else) before PV consumes them;
      // sched_barrier stops MFMA hoisting past the inline waitcnt (rule 18)
      asm volatile("s_waitcnt lgkmcnt(0)" ::: "memory");
      __builtin_amdgcn_sched_barrier(0);
      f16x8 vf0 = __builtin_shufflevector(v00, v01, 0, 1, 2, 3, 4, 5, 6, 7);
      f16x8 vf1 = __builtin_shufflevector(v10, v11, 0, 1, 2, 3, 4, 5, 6, 7);
#pragma unroll
      for (int mq = 0; mq < 2; ++mq) {
        o[mq][0] = __builtin_amdgcn_mfma_f32_16x16x32_f16(pf[mq], vf0, o[mq][0], 0, 0, 0);
        o[mq][1] = __builtin_amdgcn_mfma_f32_16x16x32_f16(pf[mq], vf1, o[mq][1], 0, 0, 0);
        osum[mq] = __builtin_amdgcn_mfma_f32_16x16x32_f16(pf[mq], onesf, osum[mq], 0, 0, 0);
      }
    }
  }
#pragma unroll
  for (int mq = 0; mq < 2; ++mq)
#pragma unroll
    for (int r = 0; r < 4; ++r) {
      float inv = 1.f / osum[mq][r];
      size_t row = rb + qb * 128 + wv * 32 + mq * 16 + quad * 4 + r;
      Op[row * 256 + h * 32 + l16]      = f2h(o[mq][0][r] * inv);
      Op[row * 256 + h * 32 + 16 + l16] = f2h(o[mq][1][r] * inv);
    }
}

// ---------------------------------------------------------------------------
// O-projection (MFMA) + bias + fp16 residual + LayerNorm -> fp16 h (+norms).
// (verified round 9)
// ---------------------------------------------------------------------------
__global__ __launch_bounds__(256, 3) void lnproj_kernel(
    const u16* __restrict__ A, const u16* __restrict__ Wt,
    const float* __restrict__ bo, const u16* __restrict__ resid,
    const float* __restrict__ g, const float* __restrict__ lb,
    u16* __restrict__ Hh, float* __restrict__ norms)
{
  __shared__ u16 Asm[64 * 32];
  __shared__ u16 Bsm[256 * 32];
  const int tid = threadIdx.x;
  const int wv = tid >> 6, ln = tid & 63;
  const int quad = ln >> 4, l16 = ln & 15;
  const size_t arow0 = (size_t)blockIdx.x * 64;
  f32x4 acc[16];
  const f32x4 VZERO = {0.f, 0.f, 0.f, 0.f};
#pragma unroll
  for (int nt = 0; nt < 16; ++nt) acc[nt] = VZERO;

  for (int k0 = 0; k0 < 256; k0 += 32) {
    __syncthreads();
    {
      int c = tid;
      int row = c >> 2, slot = c & 3;
      int kc = slot ^ swz4(row);
      ASYNC16(A + (arow0 + row) * 256 + k0 + kc * 8, Asm + c * 8);
    }
#pragma unroll
    for (int j = 0; j < 4; ++j) {
      int c = (j * 4 + wv) * 64 + ln;
      int row = c >> 2, slot = c & 3;
      int kc = slot ^ swz4(row);
      ASYNC16(Wt + (size_t)row * 256 + k0 + kc * 8, Bsm + c * 8);
    }
    __syncthreads();
    int tr = wv * 16 + l16;
    int aslot = quad ^ swz4(tr);
    f16x8 af = *(const f16x8*)(Asm + (tr * 4 + aslot) * 8);
#pragma unroll
    for (int nt = 0; nt < 16; ++nt) {
      int br = nt * 16 + l16;
      int bslot = quad ^ swz4(br);
      f16x8 bfr = *(const f16x8*)(Bsm + (br * 4 + bslot) * 8);
      acc[nt] = __builtin_amdgcn_mfma_f32_16x16x32_f16(af, bfr, acc[nt], 0, 0, 0);
    }
  }
  float gv[16], bv[16], bov[16];
#pragma unroll
  for (int nt = 0; nt < 16; ++nt) {
    int col = nt * 16 + l16;
    gv[nt] = g[col]; bv[nt] = lb[col]; bov[nt] = bo[col];
  }
#pragma unroll
  for (int r = 0; r < 4; ++r) {
    size_t row = arow0 + wv * 16 + quad * 4 + r;
    const u16* rrow = resid + row * 256;
    float vals[16]; float s = 0.f;
#pragma unroll
    for (int nt = 0; nt < 16; ++nt) {
      float v = acc[nt][r] + bov[nt] + h2f(rrow[nt * 16 + l16]);
      vals[nt] = v; s += v;
    }
#pragma unroll
    for (int m = 1; m < 16; m <<= 1) s += __shfl_xor(s, m);
    float mean = s * (1.f / 256.f);
    float sq = 0.f;
#pragma unroll
    for (int nt = 0; nt < 16; ++nt) { float d = vals[nt] - mean; sq = fmaf(d, d, sq); }
#pragma unroll
    for (int m = 1; m < 16; m <<= 1) sq += __shfl_xor(sq, m);
    float rstd = rsqrtf(sq * (1.f / 256.f) + 1e-5f);
    float ssq = 0.f;
#pragma unroll
    for (int nt = 0; nt < 16; ++nt) {
      float hv = (vals[nt] - mean) * rstd * gv[nt] + bv[nt];
      Hh[row * 256 + nt * 16 + l16] = f2h(hv);
      ssq = fmaf(hv, hv, ssq);
    }
    if (norms) {
#pragma unroll
      for (int m = 1; m < 16; m <<= 1) ssq += __shfl_xor(ssq, m);
      if (l16 == 0) norms[row] = sqrtf(ssq);
    }
  }
}

// ---------------------------------------------------------------------------
// Round 15: softmax fused into poolsum. Each (b,slice) block redundantly
// recomputes the 512-wide max/sum with code IDENTICAL to the old softmax
// kernel (bit-identical w), stores w to LDS, then pools its 64-atom slice.
// pooled is pre-zeroed by prep. Saves one dispatch + a serialization point.
// ---------------------------------------------------------------------------
__global__ __launch_bounds__(256) void poolsum_kernel(const float* __restrict__ norms,
                                                      const u16* __restrict__ h,
                                                      float* __restrict__ pooled)
{
  int b = blockIdx.x, sl = blockIdx.y, tid = threadIdx.x;
  int ln = tid & 63, wvi = tid >> 6;
  __shared__ float red[8];
  __shared__ float sw[512];
  const float* nb = norms + b * 512;
  float n0 = nb[tid], n1 = nb[tid + 256];
  float mx = fmaxf(n0, n1);
#pragma unroll
  for (int m = 1; m < 64; m <<= 1) mx = fmaxf(mx, __shfl_xor(mx, m));
  if (ln == 0) red[wvi] = mx;
  __syncthreads();
  mx = fmaxf(fmaxf(red[0], red[1]), fmaxf(red[2], red[3]));
  float e0 = __expf(n0 - mx), e1 = __expf(n1 - mx);
  float s = e0 + e1;
#pragma unroll
  for (int m = 1; m < 64; m <<= 1) s += __shfl_xor(s, m);
  if (ln == 0) red[4 + wvi] = s;
  __syncthreads();
  s = red[4] + red[5] + red[6] + red[7];
  float inv = 1.f / s;
  sw[tid] = e0 * inv;
  sw[tid + 256] = e1 * inv;
  __syncthreads();
  const u16* hb = h + ((size_t)b * 512 + sl * 64) * 256 + tid;
  const float* wb = sw + sl * 64;
  float acc = 0.f;
#pragma unroll 8
  for (int a = 0; a < 64; ++a) acc = fmaf(wb[a], h2f(hb[(size_t)a * 256]), acc);
  atomicAdd(&pooled[b * 256 + tid], acc);
}

// ---------------------------------------------------------------------------
// Round 15: fc1 + fc2 + out fused — x1 stays in LDS (identical math to the
// previous fc1_kernel -> fc23_kernel pair). Saves one dispatch.
// ---------------------------------------------------------------------------
__global__ __launch_bounds__(512) void fc_kernel(
    const float* __restrict__ pooled, const float* __restrict__ Wfc1,
    const float* __restrict__ bfc1, const float* __restrict__ Wfc2,
    const float* __restrict__ bfc2, const float* __restrict__ Wout,
    const float* __restrict__ bout, float* __restrict__ out)
{
  int b = blockIdx.x, tid = threadIdx.x;
  __shared__ float px[256];
  __shared__ float sx[512];
  __shared__ float rr[16];
  if (tid < 256) px[tid] = pooled[b * 256 + tid];
  __syncthreads();
  float a = bfc1[tid];
#pragma unroll 8
  for (int d = 0; d < 256; ++d) a = fmaf(px[d], Wfc1[d * 512 + tid], a);
  sx[tid] = fmaxf(a, 0.f);
  __syncthreads();
  a = bfc2[tid];
#pragma unroll 8
  for (int d = 0; d < 512; ++d) a = fmaf(sx[d], Wfc2[d * 512 + tid], a);
  a = fmaxf(a, 0.f);
  float p0 = a * Wout[tid * 2];
  float p1 = a * Wout[tid * 2 + 1];
  int ln = tid & 63, wvi = tid >> 6;
#pragma unroll
  for (int m = 1; m < 64; m <<= 1) { p0 += __shfl_xor(p0, m); p1 += __shfl_xor(p1, m); }
  if (ln == 0) { rr[wvi] = p0; rr[8 + wvi] = p1; }
  __syncthreads();
  if (tid == 0) {
    float s = 0.f;
#pragma unroll
    for (int i = 0; i < 8; ++i) s += rr[i];
    out[b * 2] = s + bout[0];
  }
  if (tid == 1) {
    float s = 0.f;
#pragma unroll
    for (int i = 0; i < 8; ++i) s += rr[8 + i];
    out[b * 2 + 1] = s + bout[1];
  }
}

// ---------------------------------------------------------------------------
extern "C" void kernel_launch(void* const* d_in, const int* in_sizes, int n_in,
                              void* d_out, int out_size, void* d_ws, size_t ws_size,
                              hipStream_t stream) {
  const float* trg  = (const float*)d_in[0];
  const float* src  = (const float*)d_in[1];
  const float* Wsa  = (const float*)d_in[2];
  const float* bsa  = (const float*)d_in[3];
  const float* Wea  = (const float*)d_in[4];
  const float* bea  = (const float*)d_in[5];
  const float* lng  = (const float*)d_in[6];
  const float* lnb  = (const float*)d_in[7];
  const float* Wfc1 = (const float*)d_in[8];
  const float* bfc1 = (const float*)d_in[9];
  const float* Wfc2 = (const float*)d_in[10];
  const float* bfc2 = (const float*)d_in[11];
  const float* Wout = (const float*)d_in[12];
  const float* bout = (const float*)d_in[13];
  float* out = (float*)d_out;

  const size_t M = 32768;  // B*A
  char* ws = (char*)d_ws;
  u16* trg_h = (u16*)ws;                ws += M * 256 * 2;
  u16* src_h = (u16*)ws;                ws += M * 256 * 2;
  u16* wt     = (u16*)ws;               ws += 2048 * 256 * 2;
  u16* qkv    = (u16*)ws;               ws += M * 768 * 2;
  u16* attnb  = (u16*)ws;               ws += M * 256 * 2;
  u16* hh     = (u16*)ws;               ws += M * 256 * 2;
  u16* h2h    = (u16*)ws;               ws += M * 256 * 2;
  float* norms = (float*)ws;            ws += M * 4;
  float* pooled = (float*)ws;           ws += 64 * 256 * 4;

  u16* wt_sa_qkv = wt;
  u16* wt_sa_o   = wt + 768 * 256;
  u16* wt_ea_q   = wt + 1024 * 256;
  u16* wt_ea_kv  = wt + 1280 * 256;
  u16* wt_ea_o   = wt + 1792 * 256;
  u16* kvb = qkv + M * 256;

  prep_kernel<<<10304, 256, 0, stream>>>(trg, src, Wsa, Wea, trg_h, src_h, wt, pooled);
  // self-attention
  gemm_bias_f16<<<dim3(6, 256), 256, 0, stream>>>(trg_h, wt_sa_qkv, bsa, qkv, 768);
  attn_mfma<<<2048, 256, 0, stream>>>(qkv, 768, qkv + 256, 768, qkv + 512, 768, attnb);
  lnproj_kernel<<<512, 256, 0, stream>>>(attnb, wt_sa_o, bsa + 768, trg_h, lng, lnb,
                                         hh, nullptr);
  // cross-attention: q-proj and kv-proj fused into one dispatch
  gemm_ea_kernel<<<dim3(6, 256), 256, 0, stream>>>(hh, wt_ea_q, bea, qkv,
                                                   src_h, wt_ea_kv, bea + 256, kvb);
  attn_mfma<<<2048, 256, 0, stream>>>(qkv, 256, kvb, 512, kvb + 256, 512, attnb);
  lnproj_kernel<<<512, 256, 0, stream>>>(attnb, wt_ea_o, bea + 768, hh, lng, lnb,
                                         h2h, norms);
  // pooling (softmax fused) + FC head (fc1+fc2+out fused)
  poolsum_kernel<<<dim3(64, 8), 256, 0, stream>>>(norms, h2h, pooled);
  fc_kernel<<<64, 512, 0, stream>>>(pooled, Wfc1, bfc1, Wfc2, bfc2, Wout, bout, out);

  (void)in_sizes; (void)n_in; (void)out_size; (void)ws_size;
}

// Round 17
// 306.622 us; speedup vs baseline: 1.1455x; 1.0425x over previous
//
#include <hip/hip_runtime.h>

typedef unsigned short u16;
typedef __attribute__((ext_vector_type(8))) short s16x8;      // raw 16B staging
typedef __attribute__((ext_vector_type(8))) _Float16 f16x8;   // MFMA fragments
typedef __attribute__((ext_vector_type(4))) _Float16 f16x4;
typedef __attribute__((ext_vector_type(2))) __fp16 fp16x2;    // cvt_pkrtz return type
typedef __attribute__((ext_vector_type(4))) float f32x4;

#define ASYNC16(gp, lp) \
  __builtin_amdgcn_global_load_lds((__attribute__((address_space(1))) void*)(gp), \
                                   (__attribute__((address_space(3))) void*)(lp), 16, 0, 0)

// ds_read_b64_tr_b16: group of 16 lanes reads a contiguous 4x16 u16 tile
// (per-lane addr = tile_base + l16*8 bytes); lane l16 receives column l16
// (rows j=0..3). offset:N is additive bytes.
#define TR16(dst, p, OFF) \
  asm volatile("ds_read_b64_tr_b16 %0, %1 offset:" #OFF \
               : "=v"(dst) : "v"((__attribute__((address_space(3))) const u16*)(p)))

__device__ __forceinline__ u16 f2h(float f) {
  _Float16 h = (_Float16)f;
  union { _Float16 h; u16 u; } v; v.h = h;
  return v.u;
}
__device__ __forceinline__ float h2f(u16 s) {
  union { _Float16 h; u16 u; } v; v.u = s; return (float)v.h;
}

__device__ __forceinline__ int swz4(int row) { return (row & 3) ^ ((row >> 2) & 3); }

__device__ __forceinline__ unsigned pkrtz_u32(float lo, float hi) {
  union { fp16x2 h; unsigned u; } v;
  v.h = __builtin_amdgcn_cvt_pkrtz(lo, hi);
  return v.u;
}

// ---------------------------------------------------------------------------
// prep: cast trg/src fp32->fp16; transpose+cast weights into Wt[n][k] fp16;
// also zeroes pooled (blocks 10240..10303) for the fused poolsum.
// ---------------------------------------------------------------------------
__global__ __launch_bounds__(256) void prep_kernel(
    const float* __restrict__ trg, const float* __restrict__ src,
    const float* __restrict__ Wsa, const float* __restrict__ Wea,
    u16* __restrict__ trg_h, u16* __restrict__ src_h, u16* __restrict__ wt,
    float* __restrict__ pooled)
{
  int blk = blockIdx.x, tid = threadIdx.x;
  if (blk < 8192) {
    const float* sp = (blk < 4096) ? trg : src;
    u16* dp = (blk < 4096) ? trg_h : src_h;
    size_t base = ((size_t)(blk & 4095) * 256 + tid) * 8;
    float4 a = *(const float4*)(sp + base);
    float4 c = *(const float4*)(sp + base + 4);
    s16x8 o;
    o[0] = (short)f2h(a.x); o[1] = (short)f2h(a.y);
    o[2] = (short)f2h(a.z); o[3] = (short)f2h(a.w);
    o[4] = (short)f2h(c.x); o[5] = (short)f2h(c.y);
    o[6] = (short)f2h(c.z); o[7] = (short)f2h(c.w);
    *(s16x8*)(dp + base) = o;
  } else if (blk < 10240) {
    int t = (blk - 8192) * 256 + tid;       // < 524288
    int row = t >> 8, k = t & 255;
    const float* W; int sel, col;
    if (row < 768)       { W = Wsa; sel = row >> 8;              col = row & 255; }
    else if (row < 1024) { W = Wsa; sel = 3;                     col = row & 255; }
    else if (row < 1280) { W = Wea; sel = 0;                     col = row & 255; }
    else if (row < 1792) { W = Wea; sel = ((row - 1280) >> 8) + 1; col = (row - 1280) & 255; }
    else                 { W = Wea; sel = 3;                     col = row & 255; }
    wt[(size_t)row * 256 + k] = f2h(W[sel * 65536 + k * 256 + col]);
  } else {
    int b = blk - 10240;                    // 0..63
    pooled[b * 256 + tid] = 0.f;
  }
}

// ---------------------------------------------------------------------------
// fp16 MFMA GEMM (verified round 4, BK=32): C = A @ Bt^T + bias.
// ---------------------------------------------------------------------------
__global__ __launch_bounds__(256, 3) void gemm_bias_f16(
    const u16* __restrict__ A, const u16* __restrict__ Bt,
    const float* __restrict__ bias, u16* __restrict__ C, int N)
{
  __shared__ u16 Asm[128 * 32];
  __shared__ u16 Bsm[128 * 32];
  const int tid = threadIdx.x;
  const int wv = tid >> 6, ln = tid & 63;
  const int quad = ln >> 4, l16 = ln & 15;
  const int nblk = blockIdx.x;
  const size_t arow0 = (size_t)blockIdx.y * 128;
  const size_t brow0 = (size_t)nblk * 128;
  const int wr = wv >> 1, wc = wv & 1;
  f32x4 acc[4][4];
  const f32x4 VZERO = {0.f, 0.f, 0.f, 0.f};
#pragma unroll
  for (int i = 0; i < 4; ++i)
#pragma unroll
    for (int j = 0; j < 4; ++j) acc[i][j] = VZERO;

  for (int k0 = 0; k0 < 256; k0 += 32) {
    __syncthreads();
#pragma unroll
    for (int j = 0; j < 2; ++j) {
      int c = (j * 4 + wv) * 64 + ln;
      int row = c >> 2, slot = c & 3;
      int kc = slot ^ swz4(row);
      ASYNC16(A + (arow0 + row) * 256 + k0 + kc * 8, Asm + c * 8);
      ASYNC16(Bt + (brow0 + row) * 256 + k0 + kc * 8, Bsm + c * 8);
    }
    __syncthreads();
    f16x8 af[4], bfr[4];
#pragma unroll
    for (int mt = 0; mt < 4; ++mt) {
      int tr = wr * 64 + mt * 16 + l16;
      int slot = quad ^ swz4(tr);
      af[mt] = *(const f16x8*)(Asm + (tr * 4 + slot) * 8);
    }
#pragma unroll
    for (int nt = 0; nt < 4; ++nt) {
      int tr = wc * 64 + nt * 16 + l16;
      int slot = quad ^ swz4(tr);
      bfr[nt] = *(const f16x8*)(Bsm + (tr * 4 + slot) * 8);
    }
#pragma unroll
    for (int mt = 0; mt < 4; ++mt)
#pragma unroll
      for (int nt = 0; nt < 4; ++nt)
        acc[mt][nt] = __builtin_amdgcn_mfma_f32_16x16x32_f16(af[mt], bfr[nt], acc[mt][nt], 0, 0, 0);
  }
#pragma unroll
  for (int nt = 0; nt < 4; ++nt) {
    int col = nblk * 128 + wc * 64 + nt * 16 + l16;
    float bz = bias[col];
#pragma unroll
    for (int mt = 0; mt < 4; ++mt) {
      size_t row0 = arow0 + wr * 64 + mt * 16 + quad * 4;
#pragma unroll
      for (int r = 0; r < 4; ++r)
        C[(row0 + r) * (size_t)N + col] = f2h(acc[mt][nt][r] + bz);
    }
  }
}

// ---------------------------------------------------------------------------
// ea_q (N=256, 2 nblks) + ea_kv (N=512, 4 nblks) fused into one dispatch
// (verified round 15). Same BK=32 body; per-block uniform pointer select.
// ---------------------------------------------------------------------------
__global__ __launch_bounds__(256, 3) void gemm_ea_kernel(
    const u16* __restrict__ Aq, const u16* __restrict__ Btq,
    const float* __restrict__ biasq, u16* __restrict__ Cq,
    const u16* __restrict__ Akv, const u16* __restrict__ Btkv,
    const float* __restrict__ biaskv, u16* __restrict__ Ckv)
{
  __shared__ u16 Asm[128 * 32];
  __shared__ u16 Bsm[128 * 32];
  const int tid = threadIdx.x;
  const int wv = tid >> 6, ln = tid & 63;
  const int quad = ln >> 4, l16 = ln & 15;
  const bool isq = blockIdx.x < 2;
  const int nb = isq ? blockIdx.x : blockIdx.x - 2;
  const u16* A  = isq ? Aq : Akv;
  const u16* Bt = isq ? Btq : Btkv;
  const float* bias = isq ? biasq : biaskv;
  u16* C = isq ? Cq : Ckv;
  const int N = isq ? 256 : 512;
  const size_t arow0 = (size_t)blockIdx.y * 128;
  const size_t brow0 = (size_t)nb * 128;
  const int wr = wv >> 1, wc = wv & 1;
  f32x4 acc[4][4];
  const f32x4 VZERO = {0.f, 0.f, 0.f, 0.f};
#pragma unroll
  for (int i = 0; i < 4; ++i)
#pragma unroll
    for (int j = 0; j < 4; ++j) acc[i][j] = VZERO;

  for (int k0 = 0; k0 < 256; k0 += 32) {
    __syncthreads();
#pragma unroll
    for (int j = 0; j < 2; ++j) {
      int c = (j * 4 + wv) * 64 + ln;
      int row = c >> 2, slot = c & 3;
      int kc = slot ^ swz4(row);
      ASYNC16(A + (arow0 + row) * 256 + k0 + kc * 8, Asm + c * 8);
      ASYNC16(Bt + (brow0 + row) * 256 + k0 + kc * 8, Bsm + c * 8);
    }
    __syncthreads();
    f16x8 af[4], bfr[4];
#pragma unroll
    for (int mt = 0; mt < 4; ++mt) {
      int tr = wr * 64 + mt * 16 + l16;
      int slot = quad ^ swz4(tr);
      af[mt] = *(const f16x8*)(Asm + (tr * 4 + slot) * 8);
    }
#pragma unroll
    for (int nt = 0; nt < 4; ++nt) {
      int tr = wc * 64 + nt * 16 + l16;
      int slot = quad ^ swz4(tr);
      bfr[nt] = *(const f16x8*)(Bsm + (tr * 4 + slot) * 8);
    }
#pragma unroll
    for (int mt = 0; mt < 4; ++mt)
#pragma unroll
      for (int nt = 0; nt < 4; ++nt)
        acc[mt][nt] = __builtin_amdgcn_mfma_f32_16x16x32_f16(af[mt], bfr[nt], acc[mt][nt], 0, 0, 0);
  }
#pragma unroll
  for (int nt = 0; nt < 4; ++nt) {
    int col = nb * 128 + wc * 64 + nt * 16 + l16;
    float bz = bias[col];
#pragma unroll
    for (int mt = 0; mt < 4; ++mt) {
      size_t row0 = arow0 + wr * 64 + mt * 16 + quad * 4;
#pragma unroll
      for (int r = 0; r < 4; ++r)
        C[(row0 + r) * (size_t)N + col] = f2h(acc[mt][nt][r] + bz);
    }
  }
}

// ---------------------------------------------------------------------------
// MFMA attention, no-max softmax — EXACT verified r11 (328.9us total).
// V in [key/4][d/16][4][16] subtiles (1 ds_write_b128 per item) +
// ds_read_b64_tr_b16 transpose reads; cvt_pkrtz P pack; rule-18 fence.
// ---------------------------------------------------------------------------
__global__ __launch_bounds__(256, 4) void attn_mfma(
    const u16* __restrict__ Qp, int ldq,
    const u16* __restrict__ Kp, int ldk,
    const u16* __restrict__ Vp, int ldv,
    u16* __restrict__ Op)
{
  __shared__ u16 Ks[256 * 40];
  __shared__ u16 Vs[8192];   // [key/4][d/16][key&3][d&15] subtiled, per kb
  const int tid = threadIdx.x;
  const int wv = tid >> 6, ln = tid & 63;
  const int quad = ln >> 4, l16 = ln & 15;
  const int lin = blockIdx.x;
  const int qb = (lin >> 3) & 3;
  const int g = ((lin >> 5) << 3) | (lin & 7);   // 0..511, partners share XCD
  const int h = g & 7;
  const size_t rb = (size_t)(g >> 3) * 512;
  const f32x4 VZERO = {0.f, 0.f, 0.f, 0.f};

  f16x8 qf[2];
  const _Float16 qs = (_Float16)0.25503492f;    // (1/sqrt(32)) * log2(e)
#pragma unroll
  for (int mq = 0; mq < 2; ++mq) {
    int qrow = qb * 128 + wv * 32 + mq * 16 + l16;
    qf[mq] = *(const f16x8*)(Qp + (rb + qrow) * (size_t)ldq + h * 32 + quad * 8);
#pragma unroll
    for (int j = 0; j < 8; ++j) qf[mq][j] *= qs;
  }
  f16x8 onesf;
#pragma unroll
  for (int j = 0; j < 8; ++j) onesf[j] = (_Float16)1.0f;

  f32x4 o[2][2], osum[2];
#pragma unroll
  for (int mq = 0; mq < 2; ++mq) { o[mq][0] = VZERO; o[mq][1] = VZERO; osum[mq] = VZERO; }

  for (int kb = 0; kb < 2; ++kb) {
    __syncthreads();
    for (int c = tid; c < 1024; c += 256) {
      int row = c >> 2, part = c & 3;
      s16x8 kv = *(const s16x8*)(Kp + (rb + kb * 256 + row) * (size_t)ldk + h * 32 + part * 8);
      *(s16x8*)(Ks + row * 40 + part * 8) = kv;
      s16x8 vv = *(const s16x8*)(Vp + (rb + kb * 256 + row) * (size_t)ldv + h * 32 + part * 8);
      // subtiled: elem = (key>>2)*128 + (d>>4)*64 + (key&3)*16 + (d&15)
      *(s16x8*)(Vs + (row >> 2) * 128 + (part >> 1) * 64 + (row & 3) * 16 + (part & 1) * 8) = vv;
    }
    __syncthreads();
    for (int kt = 0; kt < 8; ++kt) {
      f16x8 kf0 = *(const f16x8*)(Ks + (kt * 32 + l16) * 40 + quad * 8);
      f16x8 kf1 = *(const f16x8*)(Ks + (kt * 32 + 16 + l16) * 40 + quad * 8);
      // V transpose reads: tile base = subtile (kq = kt*8+quad*2, dg=0)
      const u16* vb = Vs + (kt * 8 + quad * 2) * 128 + l16 * 4;
      f16x4 v00, v01, v10, v11;
      TR16(v00, vb, 0);     // keys quad*8+0..3, d = l16
      TR16(v01, vb, 256);   // keys quad*8+4..7, d = l16
      TR16(v10, vb, 128);   // keys quad*8+0..3, d = 16+l16
      TR16(v11, vb, 384);   // keys quad*8+4..7, d = 16+l16
      f16x8 pf[2];
#pragma unroll
      for (int mq = 0; mq < 2; ++mq) {
        // swapped: A=K rows -> D[key][q]; lane holds q=l16, keys quad*4+r
        f32x4 s0 = __builtin_amdgcn_mfma_f32_16x16x32_f16(kf0, qf[mq], VZERO, 0, 0, 0);
        f32x4 s1 = __builtin_amdgcn_mfma_f32_16x16x32_f16(kf1, qf[mq], VZERO, 0, 0, 0);
        // exp + packed RTZ f16 convert: u0=keys 4q+{0,1}, u1=4q+{2,3},
        //                               u2=16+4q+{0,1}, u3=16+4q+{2,3}
        unsigned u0 = pkrtz_u32(__builtin_amdgcn_exp2f(s0[0]),
                                __builtin_amdgcn_exp2f(s0[1]));
        unsigned u1 = pkrtz_u32(__builtin_amdgcn_exp2f(s0[2]),
                                __builtin_amdgcn_exp2f(s0[3]));
        unsigned u2 = pkrtz_u32(__builtin_amdgcn_exp2f(s1[0]),
                                __builtin_amdgcn_exp2f(s1[1]));
        unsigned u3 = pkrtz_u32(__builtin_amdgcn_exp2f(s1[2]),
                                __builtin_amdgcn_exp2f(s1[3]));
        // in-register P rearrange to A-fragment (keys 8*quad..8*quad+7)
        asm("v_permlane32_swap_b32 %0, %1" : "+v"(u0), "+v"(u2));
        asm("v_permlane32_swap_b32 %0, %1" : "+v"(u1), "+v"(u3));
        asm("v_permlane16_swap_b32 %0, %1" : "+v"(u0), "+v"(u2));
        asm("v_permlane16_swap_b32 %0, %1" : "+v"(u1), "+v"(u3));
        union { unsigned u[4]; f16x8 f; } P;
        P.u[0] = u0; P.u[1] = u1; P.u[2] = u2; P.u[3] = u3;
        pf[mq] = P.f;
      }
      // drain the asm tr-reads (and anything else) before PV consumes them;
      // sched_barrier stops MFMA hoisting past the inline waitcnt (rule 18)
      asm volatile("s_waitcnt lgkmcnt(0)" ::: "memory");
      __builtin_amdgcn_sched_barrier(0);
      f16x8 vf0 = __builtin_shufflevector(v00, v01, 0, 1, 2, 3, 4, 5, 6, 7);
      f16x8 vf1 = __builtin_shufflevector(v10, v11, 0, 1, 2, 3, 4, 5, 6, 7);
#pragma unroll
      for (int mq = 0; mq < 2; ++mq) {
        o[mq][0] = __builtin_amdgcn_mfma_f32_16x16x32_f16(pf[mq], vf0, o[mq][0], 0, 0, 0);
        o[mq][1] = __builtin_amdgcn_mfma_f32_16x16x32_f16(pf[mq], vf1, o[mq][1], 0, 0, 0);
        osum[mq] = __builtin_amdgcn_mfma_f32_16x16x32_f16(pf[mq], onesf, osum[mq], 0, 0, 0);
      }
    }
  }
#pragma unroll
  for (int mq = 0; mq < 2; ++mq)
#pragma unroll
    for (int r = 0; r < 4; ++r) {
      float inv = 1.f / osum[mq][r];
      size_t row = rb + qb * 128 + wv * 32 + mq * 16 + quad * 4 + r;
      Op[row * 256 + h * 32 + l16]      = f2h(o[mq][0][r] * inv);
      Op[row * 256 + h * 32 + 16 + l16] = f2h(o[mq][1][r] * inv);
    }
}

// ---------------------------------------------------------------------------
// O-projection (MFMA) + bias + fp16 residual + LayerNorm -> fp16 h (+norms).
// (verified round 9)
// ---------------------------------------------------------------------------
__global__ __launch_bounds__(256, 3) void lnproj_kernel(
    const u16* __restrict__ A, const u16* __restrict__ Wt,
    const float* __restrict__ bo, const u16* __restrict__ resid,
    const float* __restrict__ g, const float* __restrict__ lb,
    u16* __restrict__ Hh, float* __restrict__ norms)
{
  __shared__ u16 Asm[64 * 32];
  __shared__ u16 Bsm[256 * 32];
  const int tid = threadIdx.x;
  const int wv = tid >> 6, ln = tid & 63;
  const int quad = ln >> 4, l16 = ln & 15;
  const size_t arow0 = (size_t)blockIdx.x * 64;
  f32x4 acc[16];
  const f32x4 VZERO = {0.f, 0.f, 0.f, 0.f};
#pragma unroll
  for (int nt = 0; nt < 16; ++nt) acc[nt] = VZERO;

  for (int k0 = 0; k0 < 256; k0 += 32) {
    __syncthreads();
    {
      int c = tid;
      int row = c >> 2, slot = c & 3;
      int kc = slot ^ swz4(row);
      ASYNC16(A + (arow0 + row) * 256 + k0 + kc * 8, Asm + c * 8);
    }
#pragma unroll
    for (int j = 0; j < 4; ++j) {
      int c = (j * 4 + wv) * 64 + ln;
      int row = c >> 2, slot = c & 3;
      int kc = slot ^ swz4(row);
      ASYNC16(Wt + (size_t)row * 256 + k0 + kc * 8, Bsm + c * 8);
    }
    __syncthreads();
    int tr = wv * 16 + l16;
    int aslot = quad ^ swz4(tr);
    f16x8 af = *(const f16x8*)(Asm + (tr * 4 + aslot) * 8);
#pragma unroll
    for (int nt = 0; nt < 16; ++nt) {
      int br = nt * 16 + l16;
      int bslot = quad ^ swz4(br);
      f16x8 bfr = *(const f16x8*)(Bsm + (br * 4 + bslot) * 8);
      acc[nt] = __builtin_amdgcn_mfma_f32_16x16x32_f16(af, bfr, acc[nt], 0, 0, 0);
    }
  }
  float gv[16], bv[16], bov[16];
#pragma unroll
  for (int nt = 0; nt < 16; ++nt) {
    int col = nt * 16 + l16;
    gv[nt] = g[col]; bv[nt] = lb[col]; bov[nt] = bo[col];
  }
#pragma unroll
  for (int r = 0; r < 4; ++r) {
    size_t row = arow0 + wv * 16 + quad * 4 + r;
    const u16* rrow = resid + row * 256;
    float vals[16]; float s = 0.f;
#pragma unroll
    for (int nt = 0; nt < 16; ++nt) {
      float v = acc[nt][r] + bov[nt] + h2f(rrow[nt * 16 + l16]);
      vals[nt] = v; s += v;
    }
#pragma unroll
    for (int m = 1; m < 16; m <<= 1) s += __shfl_xor(s, m);
    float mean = s * (1.f / 256.f);
    float sq = 0.f;
#pragma unroll
    for (int nt = 0; nt < 16; ++nt) { float d = vals[nt] - mean; sq = fmaf(d, d, sq); }
#pragma unroll
    for (int m = 1; m < 16; m <<= 1) sq += __shfl_xor(sq, m);
    float rstd = rsqrtf(sq * (1.f / 256.f) + 1e-5f);
    float ssq = 0.f;
#pragma unroll
    for (int nt = 0; nt < 16; ++nt) {
      float hv = (vals[nt] - mean) * rstd * gv[nt] + bv[nt];
      Hh[row * 256 + nt * 16 + l16] = f2h(hv);
      ssq = fmaf(hv, hv, ssq);
    }
    if (norms) {
#pragma unroll
      for (int m = 1; m < 16; m <<= 1) ssq += __shfl_xor(ssq, m);
      if (l16 == 0) norms[row] = sqrtf(ssq);
    }
  }
}

// ---------------------------------------------------------------------------
// softmax fused into poolsum (verified round 15): each (b,slice) block
// redundantly recomputes the 512-wide max/sum (bit-identical w), stores w
// in LDS, pools its 64-atom slice. pooled pre-zeroed by prep.
// ---------------------------------------------------------------------------
__global__ __launch_bounds__(256) void poolsum_kernel(const float* __restrict__ norms,
                                                      const u16* __restrict__ h,
                                                      float* __restrict__ pooled)
{
  int b = blockIdx.x, sl = blockIdx.y, tid = threadIdx.x;
  int ln = tid & 63, wvi = tid >> 6;
  __shared__ float red[8];
  __shared__ float sw[512];
  const float* nb = norms + b * 512;
  float n0 = nb[tid], n1 = nb[tid + 256];
  float mx = fmaxf(n0, n1);
#pragma unroll
  for (int m = 1; m < 64; m <<= 1) mx = fmaxf(mx, __shfl_xor(mx, m));
  if (ln == 0) red[wvi] = mx;
  __syncthreads();
  mx = fmaxf(fmaxf(red[0], red[1]), fmaxf(red[2], red[3]));
  float e0 = __expf(n0 - mx), e1 = __expf(n1 - mx);
  float s = e0 + e1;
#pragma unroll
  for (int m = 1; m < 64; m <<= 1) s += __shfl_xor(s, m);
  if (ln == 0) red[4 + wvi] = s;
  __syncthreads();
  s = red[4] + red[5] + red[6] + red[7];
  float inv = 1.f / s;
  sw[tid] = e0 * inv;
  sw[tid + 256] = e1 * inv;
  __syncthreads();
  const u16* hb = h + ((size_t)b * 512 + sl * 64) * 256 + tid;
  const float* wb = sw + sl * 64;
  float acc = 0.f;
#pragma unroll 8
  for (int a = 0; a < 64; ++a) acc = fmaf(wb[a], h2f(hb[(size_t)a * 256]), acc);
  atomicAdd(&pooled[b * 256 + tid], acc);
}

// ---------------------------------------------------------------------------
// Round 16: FC stack re-parallelized. r15 PMC exposed fc_kernel as the top
// dispatch (53.7us @ 1.5% HBM, 2% VALU, 5% occupancy): 64 blocks x serial
// 768-long fmaf chains with exposed per-iteration load latency. Fix:
// 1024 threads/block, K split across 2 groups (q=tid>>9, j=tid&511):
// fc1 chains 256->128, fc2 512->256; partials combined via LDS. Lanes keep
// consecutive-j coalesced weight reads. fp32 reassociation (~1e-7) only.
// ---------------------------------------------------------------------------
__global__ __launch_bounds__(1024) void fc_kernel(
    const float* __restrict__ pooled, const float* __restrict__ Wfc1,
    const float* __restrict__ bfc1, const float* __restrict__ Wfc2,
    const float* __restrict__ bfc2, const float* __restrict__ Wout,
    const float* __restrict__ bout, float* __restrict__ out)
{
  int b = blockIdx.x, tid = threadIdx.x;
  const int q = tid >> 9, j = tid & 511;
  __shared__ float px[256];
  __shared__ float sx[512];
  __shared__ float part[1024];
  __shared__ float rr[16];
  if (tid < 256) px[tid] = pooled[b * 256 + tid];
  __syncthreads();
  // fc1: thread (q,j) sums d in [q*128, q*128+128)
  {
    float a = 0.f;
    const float* wp = Wfc1 + (size_t)(q * 128) * 512 + j;
#pragma unroll 8
    for (int i = 0; i < 128; ++i) a = fmaf(px[q * 128 + i], wp[i * 512], a);
    part[tid] = a;
  }
  __syncthreads();
  if (tid < 512) sx[tid] = fmaxf(part[tid] + part[tid + 512] + bfc1[tid], 0.f);
  __syncthreads();
  // fc2: thread (q,j) sums d in [q*256, q*256+256)
  {
    float a = 0.f;
    const float* wp = Wfc2 + (size_t)(q * 256) * 512 + j;
#pragma unroll 8
    for (int i = 0; i < 256; ++i) a = fmaf(sx[q * 256 + i], wp[i * 512], a);
    part[tid] = a;
  }
  __syncthreads();
  if (tid < 512) {
    float a = fmaxf(part[tid] + part[tid + 512] + bfc2[tid], 0.f);
    float p0 = a * Wout[tid * 2];
    float p1 = a * Wout[tid * 2 + 1];
    int ln = tid & 63, wvi = tid >> 6;
#pragma unroll
    for (int m = 1; m < 64; m <<= 1) { p0 += __shfl_xor(p0, m); p1 += __shfl_xor(p1, m); }
    if (ln == 0) { rr[wvi] = p0; rr[8 + wvi] = p1; }
  }
  __syncthreads();
  if (tid == 0) {
    float s = 0.f;
#pragma unroll
    for (int i = 0; i < 8; ++i) s += rr[i];
    out[b * 2] = s + bout[0];
  }
  if (tid == 1) {
    float s = 0.f;
#pragma unroll
    for (int i = 0; i < 8; ++i) s += rr[8 + i];
    out[b * 2 + 1] = s + bout[1];
  }
}

// ---------------------------------------------------------------------------
extern "C" void kernel_launch(void* const* d_in, const int* in_sizes, int n_in,
                              void* d_out, int out_size, void* d_ws, size_t ws_size,
                              hipStream_t stream) {
  const float* trg  = (const float*)d_in[0];
  const float* src  = (const float*)d_in[1];
  const float* Wsa  = (const float*)d_in[2];
  const float* bsa  = (const float*)d_in[3];
  const float* Wea  = (const float*)d_in[4];
  const float* bea  = (const float*)d_in[5];
  const float* lng  = (const float*)d_in[6];
  const float* lnb  = (const float*)d_in[7];
  const float* Wfc1 = (const float*)d_in[8];
  const float* bfc1 = (const float*)d_in[9];
  const float* Wfc2 = (const float*)d_in[10];
  const float* bfc2 = (const float*)d_in[11];
  const float* Wout = (const float*)d_in[12];
  const float* bout = (const float*)d_in[13];
  float* out = (float*)d_out;

  const size_t M = 32768;  // B*A
  char* ws = (char*)d_ws;
  u16* trg_h = (u16*)ws;                ws += M * 256 * 2;
  u16* src_h = (u16*)ws;                ws += M * 256 * 2;
  u16* wt     = (u16*)ws;               ws += 2048 * 256 * 2;
  u16* qkv    = (u16*)ws;               ws += M * 768 * 2;
  u16* attnb  = (u16*)ws;               ws += M * 256 * 2;
  u16* hh     = (u16*)ws;               ws += M * 256 * 2;
  u16* h2h    = (u16*)ws;               ws += M * 256 * 2;
  float* norms = (float*)ws;            ws += M * 4;
  float* pooled = (float*)ws;           ws += 64 * 256 * 4;

  u16* wt_sa_qkv = wt;
  u16* wt_sa_o   = wt + 768 * 256;
  u16* wt_ea_q   = wt + 1024 * 256;
  u16* wt_ea_kv  = wt + 1280 * 256;
  u16* wt_ea_o   = wt + 1792 * 256;
  u16* kvb = qkv + M * 256;

  prep_kernel<<<10304, 256, 0, stream>>>(trg, src, Wsa, Wea, trg_h, src_h, wt, pooled);
  // self-attention
  gemm_bias_f16<<<dim3(6, 256), 256, 0, stream>>>(trg_h, wt_sa_qkv, bsa, qkv, 768);
  attn_mfma<<<2048, 256, 0, stream>>>(qkv, 768, qkv + 256, 768, qkv + 512, 768, attnb);
  lnproj_kernel<<<512, 256, 0, stream>>>(attnb, wt_sa_o, bsa + 768, trg_h, lng, lnb,
                                         hh, nullptr);
  // cross-attention: q-proj and kv-proj fused into one dispatch
  gemm_ea_kernel<<<dim3(6, 256), 256, 0, stream>>>(hh, wt_ea_q, bea, qkv,
                                                   src_h, wt_ea_kv, bea + 256, kvb);
  attn_mfma<<<2048, 256, 0, stream>>>(qkv, 256, kvb, 512, kvb + 256, 512, attnb);
  lnproj_kernel<<<512, 256, 0, stream>>>(attnb, wt_ea_o, bea + 768, hh, lng, lnb,
                                         h2h, norms);
  // pooling (softmax fused) + FC head (split-K parallel)
  poolsum_kernel<<<dim3(64, 8), 256, 0, stream>>>(norms, h2h, pooled);
  fc_kernel<<<64, 1024, 0, stream>>>(pooled, Wfc1, bfc1, Wfc2, bfc2, Wout, bout, out);

  (void)in_sizes; (void)n_in; (void)out_size; (void)ws_size;
}

// Round 21
// 305.574 us; speedup vs baseline: 1.1494x; 1.0034x over previous
//
#include <hip/hip_runtime.h>

typedef unsigned short u16;
typedef __attribute__((ext_vector_type(8))) short s16x8;      // raw 16B staging
typedef __attribute__((ext_vector_type(8))) _Float16 f16x8;   // MFMA fragments
typedef __attribute__((ext_vector_type(4))) _Float16 f16x4;
typedef __attribute__((ext_vector_type(2))) __fp16 fp16x2;    // cvt_pkrtz return type
typedef __attribute__((ext_vector_type(4))) float f32x4;

#define ASYNC16(gp, lp) \
  __builtin_amdgcn_global_load_lds((__attribute__((address_space(1))) void*)(gp), \
                                   (__attribute__((address_space(3))) void*)(lp), 16, 0, 0)

// ds_read_b64_tr_b16: group of 16 lanes reads a contiguous 4x16 u16 tile
// (per-lane addr = tile_base + l16*8 bytes); lane l16 receives column l16
// (rows j=0..3). offset:N is additive bytes.
#define TR16(dst, p, OFF) \
  asm volatile("ds_read_b64_tr_b16 %0, %1 offset:" #OFF \
               : "=v"(dst) : "v"((__attribute__((address_space(3))) const u16*)(p)))

__device__ __forceinline__ u16 f2h(float f) {
  _Float16 h = (_Float16)f;
  union { _Float16 h; u16 u; } v; v.h = h;
  return v.u;
}
__device__ __forceinline__ float h2f(u16 s) {
  union { _Float16 h; u16 u; } v; v.u = s; return (float)v.h;
}

__device__ __forceinline__ int swz4(int row) { return (row & 3) ^ ((row >> 2) & 3); }

__device__ __forceinline__ unsigned pkrtz_u32(float lo, float hi) {
  union { fp16x2 h; unsigned u; } v;
  v.h = __builtin_amdgcn_cvt_pkrtz(lo, hi);
  return v.u;
}

// ---------------------------------------------------------------------------
// prep: cast trg/src fp32->fp16; transpose+cast weights into Wt[n][k] fp16;
// also zeroes pooled (blocks 10240..10303) for the fused poolsum.
// ---------------------------------------------------------------------------
__global__ __launch_bounds__(256) void prep_kernel(
    const float* __restrict__ trg, const float* __restrict__ src,
    const float* __restrict__ Wsa, const float* __restrict__ Wea,
    u16* __restrict__ trg_h, u16* __restrict__ src_h, u16* __restrict__ wt,
    float* __restrict__ pooled)
{
  int blk = blockIdx.x, tid = threadIdx.x;
  if (blk < 8192) {
    const float* sp = (blk < 4096) ? trg : src;
    u16* dp = (blk < 4096) ? trg_h : src_h;
    size_t base = ((size_t)(blk & 4095) * 256 + tid) * 8;
    float4 a = *(const float4*)(sp + base);
    float4 c = *(const float4*)(sp + base + 4);
    s16x8 o;
    o[0] = (short)f2h(a.x); o[1] = (short)f2h(a.y);
    o[2] = (short)f2h(a.z); o[3] = (short)f2h(a.w);
    o[4] = (short)f2h(c.x); o[5] = (short)f2h(c.y);
    o[6] = (short)f2h(c.z); o[7] = (short)f2h(c.w);
    *(s16x8*)(dp + base) = o;
  } else if (blk < 10240) {
    int t = (blk - 8192) * 256 + tid;       // < 524288
    int row = t >> 8, k = t & 255;
    const float* W; int sel, col;
    if (row < 768)       { W = Wsa; sel = row >> 8;              col = row & 255; }
    else if (row < 1024) { W = Wsa; sel = 3;                     col = row & 255; }
    else if (row < 1280) { W = Wea; sel = 0;                     col = row & 255; }
    else if (row < 1792) { W = Wea; sel = ((row - 1280) >> 8) + 1; col = (row - 1280) & 255; }
    else                 { W = Wea; sel = 3;                     col = row & 255; }
    wt[(size_t)row * 256 + k] = f2h(W[sel * 65536 + k * 256 + col]);
  } else {
    int b = blk - 10240;                    // 0..63
    pooled[b * 256 + tid] = 0.f;
  }
}

// ---------------------------------------------------------------------------
// fp16 MFMA GEMM (verified round 4, BK=32): C = A @ Bt^T + bias.
// ---------------------------------------------------------------------------
__global__ __launch_bounds__(256, 3) void gemm_bias_f16(
    const u16* __restrict__ A, const u16* __restrict__ Bt,
    const float* __restrict__ bias, u16* __restrict__ C, int N)
{
  __shared__ u16 Asm[128 * 32];
  __shared__ u16 Bsm[128 * 32];
  const int tid = threadIdx.x;
  const int wv = tid >> 6, ln = tid & 63;
  const int quad = ln >> 4, l16 = ln & 15;
  const int nblk = blockIdx.x;
  const size_t arow0 = (size_t)blockIdx.y * 128;
  const size_t brow0 = (size_t)nblk * 128;
  const int wr = wv >> 1, wc = wv & 1;
  f32x4 acc[4][4];
  const f32x4 VZERO = {0.f, 0.f, 0.f, 0.f};
#pragma unroll
  for (int i = 0; i < 4; ++i)
#pragma unroll
    for (int j = 0; j < 4; ++j) acc[i][j] = VZERO;

  for (int k0 = 0; k0 < 256; k0 += 32) {
    __syncthreads();
#pragma unroll
    for (int j = 0; j < 2; ++j) {
      int c = (j * 4 + wv) * 64 + ln;
      int row = c >> 2, slot = c & 3;
      int kc = slot ^ swz4(row);
      ASYNC16(A + (arow0 + row) * 256 + k0 + kc * 8, Asm + c * 8);
      ASYNC16(Bt + (brow0 + row) * 256 + k0 + kc * 8, Bsm + c * 8);
    }
    __syncthreads();
    f16x8 af[4], bfr[4];
#pragma unroll
    for (int mt = 0; mt < 4; ++mt) {
      int tr = wr * 64 + mt * 16 + l16;
      int slot = quad ^ swz4(tr);
      af[mt] = *(const f16x8*)(Asm + (tr * 4 + slot) * 8);
    }
#pragma unroll
    for (int nt = 0; nt < 4; ++nt) {
      int tr = wc * 64 + nt * 16 + l16;
      int slot = quad ^ swz4(tr);
      bfr[nt] = *(const f16x8*)(Bsm + (tr * 4 + slot) * 8);
    }
#pragma unroll
    for (int mt = 0; mt < 4; ++mt)
#pragma unroll
      for (int nt = 0; nt < 4; ++nt)
        acc[mt][nt] = __builtin_amdgcn_mfma_f32_16x16x32_f16(af[mt], bfr[nt], acc[mt][nt], 0, 0, 0);
  }
#pragma unroll
  for (int nt = 0; nt < 4; ++nt) {
    int col = nblk * 128 + wc * 64 + nt * 16 + l16;
    float bz = bias[col];
#pragma unroll
    for (int mt = 0; mt < 4; ++mt) {
      size_t row0 = arow0 + wr * 64 + mt * 16 + quad * 4;
#pragma unroll
      for (int r = 0; r < 4; ++r)
        C[(row0 + r) * (size_t)N + col] = f2h(acc[mt][nt][r] + bz);
    }
  }
}

// ---------------------------------------------------------------------------
// ea_q (N=256, 2 nblks) + ea_kv (N=512, 4 nblks) fused into one dispatch
// (verified round 15). Same BK=32 body; per-block uniform pointer select.
// ---------------------------------------------------------------------------
__global__ __launch_bounds__(256, 3) void gemm_ea_kernel(
    const u16* __restrict__ Aq, const u16* __restrict__ Btq,
    const float* __restrict__ biasq, u16* __restrict__ Cq,
    const u16* __restrict__ Akv, const u16* __restrict__ Btkv,
    const float* __restrict__ biaskv, u16* __restrict__ Ckv)
{
  __shared__ u16 Asm[128 * 32];
  __shared__ u16 Bsm[128 * 32];
  const int tid = threadIdx.x;
  const int wv = tid >> 6, ln = tid & 63;
  const int quad = ln >> 4, l16 = ln & 15;
  const bool isq = blockIdx.x < 2;
  const int nb = isq ? blockIdx.x : blockIdx.x - 2;
  const u16* A  = isq ? Aq : Akv;
  const u16* Bt = isq ? Btq : Btkv;
  const float* bias = isq ? biasq : biaskv;
  u16* C = isq ? Cq : Ckv;
  const int N = isq ? 256 : 512;
  const size_t arow0 = (size_t)blockIdx.y * 128;
  const size_t brow0 = (size_t)nb * 128;
  const int wr = wv >> 1, wc = wv & 1;
  f32x4 acc[4][4];
  const f32x4 VZERO = {0.f, 0.f, 0.f, 0.f};
#pragma unroll
  for (int i = 0; i < 4; ++i)
#pragma unroll
    for (int j = 0; j < 4; ++j) acc[i][j] = VZERO;

  for (int k0 = 0; k0 < 256; k0 += 32) {
    __syncthreads();
#pragma unroll
    for (int j = 0; j < 2; ++j) {
      int c = (j * 4 + wv) * 64 + ln;
      int row = c >> 2, slot = c & 3;
      int kc = slot ^ swz4(row);
      ASYNC16(A + (arow0 + row) * 256 + k0 + kc * 8, Asm + c * 8);
      ASYNC16(Bt + (brow0 + row) * 256 + k0 + kc * 8, Bsm + c * 8);
    }
    __syncthreads();
    f16x8 af[4], bfr[4];
#pragma unroll
    for (int mt = 0; mt < 4; ++mt) {
      int tr = wr * 64 + mt * 16 + l16;
      int slot = quad ^ swz4(tr);
      af[mt] = *(const f16x8*)(Asm + (tr * 4 + slot) * 8);
    }
#pragma unroll
    for (int nt = 0; nt < 4; ++nt) {
      int tr = wc * 64 + nt * 16 + l16;
      int slot = quad ^ swz4(tr);
      bfr[nt] = *(const f16x8*)(Bsm + (tr * 4 + slot) * 8);
    }
#pragma unroll
    for (int mt = 0; mt < 4; ++mt)
#pragma unroll
      for (int nt = 0; nt < 4; ++nt)
        acc[mt][nt] = __builtin_amdgcn_mfma_f32_16x16x32_f16(af[mt], bfr[nt], acc[mt][nt], 0, 0, 0);
  }
#pragma unroll
  for (int nt = 0; nt < 4; ++nt) {
    int col = nb * 128 + wc * 64 + nt * 16 + l16;
    float bz = bias[col];
#pragma unroll
    for (int mt = 0; mt < 4; ++mt) {
      size_t row0 = arow0 + wr * 64 + mt * 16 + quad * 4;
#pragma unroll
      for (int r = 0; r < 4; ++r)
        C[(row0 + r) * (size_t)N + col] = f2h(acc[mt][nt][r] + bz);
    }
  }
}

// ---------------------------------------------------------------------------
// MFMA attention, no-max softmax.
// Round 18: Ks re-laid out from padded [256][40] (20KB, 2-way-free reads)
// to the VERIFIED gemm XOR-swizzle layout [256][32] (16KB): slot s holds
// col-group s^swz4(row), staged by inverse-swizzling the GLOBAL source part
// (rule 21 both-sides), read at slot quad^swz4(row) — byte-for-byte the
// pattern proven in gemm_bias_f16 since r4. Total LDS 36KB -> exactly 32KB
// -> 5 blocks/CU (+25% waves) on a latency-bound kernel (r1 PMC: all pipes
// <55%). Math bit-identical. V subtile + tr-read + pkrtz + permlane kept.
// ---------------------------------------------------------------------------
__global__ __launch_bounds__(256, 5) void attn_mfma(
    const u16* __restrict__ Qp, int ldq,
    const u16* __restrict__ Kp, int ldk,
    const u16* __restrict__ Vp, int ldv,
    u16* __restrict__ Op)
{
  __shared__ u16 Ks[256 * 32];   // XOR-swizzled col groups (gemm pattern)
  __shared__ u16 Vs[8192];       // [key/4][d/16][key&3][d&15] subtiled
  const int tid = threadIdx.x;
  const int wv = tid >> 6, ln = tid & 63;
  const int quad = ln >> 4, l16 = ln & 15;
  const int lin = blockIdx.x;
  const int qb = (lin >> 3) & 3;
  const int g = ((lin >> 5) << 3) | (lin & 7);   // 0..511, partners share XCD
  const int h = g & 7;
  const size_t rb = (size_t)(g >> 3) * 512;
  const f32x4 VZERO = {0.f, 0.f, 0.f, 0.f};

  f16x8 qf[2];
  const _Float16 qs = (_Float16)0.25503492f;    // (1/sqrt(32)) * log2(e)
#pragma unroll
  for (int mq = 0; mq < 2; ++mq) {
    int qrow = qb * 128 + wv * 32 + mq * 16 + l16;
    qf[mq] = *(const f16x8*)(Qp + (rb + qrow) * (size_t)ldq + h * 32 + quad * 8);
#pragma unroll
    for (int j = 0; j < 8; ++j) qf[mq][j] *= qs;
  }
  f16x8 onesf;
#pragma unroll
  for (int j = 0; j < 8; ++j) onesf[j] = (_Float16)1.0f;

  f32x4 o[2][2], osum[2];
#pragma unroll
  for (int mq = 0; mq < 2; ++mq) { o[mq][0] = VZERO; o[mq][1] = VZERO; osum[mq] = VZERO; }

  for (int kb = 0; kb < 2; ++kb) {
    __syncthreads();
    for (int c = tid; c < 1024; c += 256) {
      int row = c >> 2, part = c & 3;
      int kc = part ^ swz4(row);   // inverse swizzle on global source
      s16x8 kv = *(const s16x8*)(Kp + (rb + kb * 256 + row) * (size_t)ldk + h * 32 + kc * 8);
      *(s16x8*)(Ks + c * 8) = kv;  // linear LDS dest: slot=part holds col kc
      s16x8 vv = *(const s16x8*)(Vp + (rb + kb * 256 + row) * (size_t)ldv + h * 32 + part * 8);
      // subtiled: elem = (key>>2)*128 + (d>>4)*64 + (key&3)*16 + (d&15)
      *(s16x8*)(Vs + (row >> 2) * 128 + (part >> 1) * 64 + (row & 3) * 16 + (part & 1) * 8) = vv;
    }
    __syncthreads();
    for (int kt = 0; kt < 8; ++kt) {
      int r0 = kt * 32 + l16, r1 = kt * 32 + 16 + l16;
      f16x8 kf0 = *(const f16x8*)(Ks + (r0 * 4 + (quad ^ swz4(r0))) * 8);
      f16x8 kf1 = *(const f16x8*)(Ks + (r1 * 4 + (quad ^ swz4(r1))) * 8);
      // V transpose reads: tile base = subtile (kq = kt*8+quad*2, dg=0)
      const u16* vb = Vs + (kt * 8 + quad * 2) * 128 + l16 * 4;
      f16x4 v00, v01, v10, v11;
      TR16(v00, vb, 0);     // keys quad*8+0..3, d = l16
      TR16(v01, vb, 256);   // keys quad*8+4..7, d = l16
      TR16(v10, vb, 128);   // keys quad*8+0..3, d = 16+l16
      TR16(v11, vb, 384);   // keys quad*8+4..7, d = 16+l16
      f16x8 pf[2];
#pragma unroll
      for (int mq = 0; mq < 2; ++mq) {
        // swapped: A=K rows -> D[key][q]; lane holds q=l16, keys quad*4+r
        f32x4 s0 = __builtin_amdgcn_mfma_f32_16x16x32_f16(kf0, qf[mq], VZERO, 0, 0, 0);
        f32x4 s1 = __builtin_amdgcn_mfma_f32_16x16x32_f16(kf1, qf[mq], VZERO, 0, 0, 0);
        // exp + packed RTZ f16 convert: u0=keys 4q+{0,1}, u1=4q+{2,3},
        //                               u2=16+4q+{0,1}, u3=16+4q+{2,3}
        unsigned u0 = pkrtz_u32(__builtin_amdgcn_exp2f(s0[0]),
                                __builtin_amdgcn_exp2f(s0[1]));
        unsigned u1 = pkrtz_u32(__builtin_amdgcn_exp2f(s0[2]),
                                __builtin_amdgcn_exp2f(s0[3]));
        unsigned u2 = pkrtz_u32(__builtin_amdgcn_exp2f(s1[0]),
                                __builtin_amdgcn_exp2f(s1[1]));
        unsigned u3 = pkrtz_u32(__builtin_amdgcn_exp2f(s1[2]),
                                __builtin_amdgcn_exp2f(s1[3]));
        // in-register P rearrange to A-fragment (keys 8*quad..8*quad+7)
        asm("v_permlane32_swap_b32 %0, %1" : "+v"(u0), "+v"(u2));
        asm("v_permlane32_swap_b32 %0, %1" : "+v"(u1), "+v"(u3));
        asm("v_permlane16_swap_b32 %0, %1" : "+v"(u0), "+v"(u2));
        asm("v_permlane16_swap_b32 %0, %1" : "+v"(u1), "+v"(u3));
        union { unsigned u[4]; f16x8 f; } P;
        P.u[0] = u0; P.u[1] = u1; P.u[2] = u2; P.u[3] = u3;
        pf[mq] = P.f;
      }
      // drain the asm tr-reads (and anything else) before PV consumes them;
      // sched_barrier stops MFMA hoisting past the inline waitcnt (rule 18)
      asm volatile("s_waitcnt lgkmcnt(0)" ::: "memory");
      __builtin_amdgcn_sched_barrier(0);
      f16x8 vf0 = __builtin_shufflevector(v00, v01, 0, 1, 2, 3, 4, 5, 6, 7);
      f16x8 vf1 = __builtin_shufflevector(v10, v11, 0, 1, 2, 3, 4, 5, 6, 7);
#pragma unroll
      for (int mq = 0; mq < 2; ++mq) {
        o[mq][0] = __builtin_amdgcn_mfma_f32_16x16x32_f16(pf[mq], vf0, o[mq][0], 0, 0, 0);
        o[mq][1] = __builtin_amdgcn_mfma_f32_16x16x32_f16(pf[mq], vf1, o[mq][1], 0, 0, 0);
        osum[mq] = __builtin_amdgcn_mfma_f32_16x16x32_f16(pf[mq], onesf, osum[mq], 0, 0, 0);
      }
    }
  }
#pragma unroll
  for (int mq = 0; mq < 2; ++mq)
#pragma unroll
    for (int r = 0; r < 4; ++r) {
      float inv = 1.f / osum[mq][r];
      size_t row = rb + qb * 128 + wv * 32 + mq * 16 + quad * 4 + r;
      Op[row * 256 + h * 32 + l16]      = f2h(o[mq][0][r] * inv);
      Op[row * 256 + h * 32 + 16 + l16] = f2h(o[mq][1][r] * inv);
    }
}

// ---------------------------------------------------------------------------
// O-projection (MFMA) + bias + fp16 residual + LayerNorm -> fp16 h (+norms).
// (verified round 9)
// ---------------------------------------------------------------------------
__global__ __launch_bounds__(256, 3) void lnproj_kernel(
    const u16* __restrict__ A, const u16* __restrict__ Wt,
    const float* __restrict__ bo, const u16* __restrict__ resid,
    const float* __restrict__ g, const float* __restrict__ lb,
    u16* __restrict__ Hh, float* __restrict__ norms)
{
  __shared__ u16 Asm[64 * 32];
  __shared__ u16 Bsm[256 * 32];
  const int tid = threadIdx.x;
  const int wv = tid >> 6, ln = tid & 63;
  const int quad = ln >> 4, l16 = ln & 15;
  const size_t arow0 = (size_t)blockIdx.x * 64;
  f32x4 acc[16];
  const f32x4 VZERO = {0.f, 0.f, 0.f, 0.f};
#pragma unroll
  for (int nt = 0; nt < 16; ++nt) acc[nt] = VZERO;

  for (int k0 = 0; k0 < 256; k0 += 32) {
    __syncthreads();
    {
      int c = tid;
      int row = c >> 2, slot = c & 3;
      int kc = slot ^ swz4(row);
      ASYNC16(A + (arow0 + row) * 256 + k0 + kc * 8, Asm + c * 8);
    }
#pragma unroll
    for (int j = 0; j < 4; ++j) {
      int c = (j * 4 + wv) * 64 + ln;
      int row = c >> 2, slot = c & 3;
      int kc = slot ^ swz4(row);
      ASYNC16(Wt + (size_t)row * 256 + k0 + kc * 8, Bsm + c * 8);
    }
    __syncthreads();
    int tr = wv * 16 + l16;
    int aslot = quad ^ swz4(tr);
    f16x8 af = *(const f16x8*)(Asm + (tr * 4 + aslot) * 8);
#pragma unroll
    for (int nt = 0; nt < 16; ++nt) {
      int br = nt * 16 + l16;
      int bslot = quad ^ swz4(br);
      f16x8 bfr = *(const f16x8*)(Bsm + (br * 4 + bslot) * 8);
      acc[nt] = __builtin_amdgcn_mfma_f32_16x16x32_f16(af, bfr, acc[nt], 0, 0, 0);
    }
  }
  float gv[16], bv[16], bov[16];
#pragma unroll
  for (int nt = 0; nt < 16; ++nt) {
    int col = nt * 16 + l16;
    gv[nt] = g[col]; bv[nt] = lb[col]; bov[nt] = bo[col];
  }
#pragma unroll
  for (int r = 0; r < 4; ++r) {
    size_t row = arow0 + wv * 16 + quad * 4 + r;
    const u16* rrow = resid + row * 256;
    float vals[16]; float s = 0.f;
#pragma unroll
    for (int nt = 0; nt < 16; ++nt) {
      float v = acc[nt][r] + bov[nt] + h2f(rrow[nt * 16 + l16]);
      vals[nt] = v; s += v;
    }
#pragma unroll
    for (int m = 1; m < 16; m <<= 1) s += __shfl_xor(s, m);
    float mean = s * (1.f / 256.f);
    float sq = 0.f;
#pragma unroll
    for (int nt = 0; nt < 16; ++nt) { float d = vals[nt] - mean; sq = fmaf(d, d, sq); }
#pragma unroll
    for (int m = 1; m < 16; m <<= 1) sq += __shfl_xor(sq, m);
    float rstd = rsqrtf(sq * (1.f / 256.f) + 1e-5f);
    float ssq = 0.f;
#pragma unroll
    for (int nt = 0; nt < 16; ++nt) {
      float hv = (vals[nt] - mean) * rstd * gv[nt] + bv[nt];
      Hh[row * 256 + nt * 16 + l16] = f2h(hv);
      ssq = fmaf(hv, hv, ssq);
    }
    if (norms) {
#pragma unroll
      for (int m = 1; m < 16; m <<= 1) ssq += __shfl_xor(ssq, m);
      if (l16 == 0) norms[row] = sqrtf(ssq);
    }
  }
}

// ---------------------------------------------------------------------------
// softmax fused into poolsum (verified round 15): each (b,slice) block
// redundantly recomputes the 512-wide max/sum (bit-identical w), stores w
// in LDS, pools its 64-atom slice. pooled pre-zeroed by prep.
// ---------------------------------------------------------------------------
__global__ __launch_bounds__(256) void poolsum_kernel(const float* __restrict__ norms,
                                                      const u16* __restrict__ h,
                                                      float* __restrict__ pooled)
{
  int b = blockIdx.x, sl = blockIdx.y, tid = threadIdx.x;
  int ln = tid & 63, wvi = tid >> 6;
  __shared__ float red[8];
  __shared__ float sw[512];
  const float* nb = norms + b * 512;
  float n0 = nb[tid], n1 = nb[tid + 256];
  float mx = fmaxf(n0, n1);
#pragma unroll
  for (int m = 1; m < 64; m <<= 1) mx = fmaxf(mx, __shfl_xor(mx, m));
  if (ln == 0) red[wvi] = mx;
  __syncthreads();
  mx = fmaxf(fmaxf(red[0], red[1]), fmaxf(red[2], red[3]));
  float e0 = __expf(n0 - mx), e1 = __expf(n1 - mx);
  float s = e0 + e1;
#pragma unroll
  for (int m = 1; m < 64; m <<= 1) s += __shfl_xor(s, m);
  if (ln == 0) red[4 + wvi] = s;
  __syncthreads();
  s = red[4] + red[5] + red[6] + red[7];
  float inv = 1.f / s;
  sw[tid] = e0 * inv;
  sw[tid + 256] = e1 * inv;
  __syncthreads();
  const u16* hb = h + ((size_t)b * 512 + sl * 64) * 256 + tid;
  const float* wb = sw + sl * 64;
  float acc = 0.f;
#pragma unroll 8
  for (int a = 0; a < 64; ++a) acc = fmaf(wb[a], h2f(hb[(size_t)a * 256]), acc);
  atomicAdd(&pooled[b * 256 + tid], acc);
}

// ---------------------------------------------------------------------------
// Round 18: fc split-K (r16, verified -13us) + ILP-2: two independent
// accumulators per thread halve the dependent fmaf chain again (fc1 128->64,
// fc2 256->128 links). fp32 reassociation only (~1e-7).
// ---------------------------------------------------------------------------
__global__ __launch_bounds__(1024) void fc_kernel(
    const float* __restrict__ pooled, const float* __restrict__ Wfc1,
    const float* __restrict__ bfc1, const float* __restrict__ Wfc2,
    const float* __restrict__ bfc2, const float* __restrict__ Wout,
    const float* __restrict__ bout, float* __restrict__ out)
{
  int b = blockIdx.x, tid = threadIdx.x;
  const int q = tid >> 9, j = tid & 511;
  __shared__ float px[256];
  __shared__ float sx[512];
  __shared__ float part[1024];
  __shared__ float rr[16];
  if (tid < 256) px[tid] = pooled[b * 256 + tid];
  __syncthreads();
  // fc1: thread (q,j) sums d in [q*128, q*128+128), 2 independent chains
  {
    float a0 = 0.f, a1 = 0.f;
    const float* wp = Wfc1 + (size_t)(q * 128) * 512 + j;
#pragma unroll 8
    for (int i = 0; i < 128; i += 2) {
      a0 = fmaf(px[q * 128 + i],     wp[i * 512],       a0);
      a1 = fmaf(px[q * 128 + i + 1], wp[(i + 1) * 512], a1);
    }
    part[tid] = a0 + a1;
  }
  __syncthreads();
  if (tid < 512) sx[tid] = fmaxf(part[tid] + part[tid + 512] + bfc1[tid], 0.f);
  __syncthreads();
  // fc2: thread (q,j) sums d in [q*256, q*256+256), 2 independent chains
  {
    float a0 = 0.f, a1 = 0.f;
    const float* wp = Wfc2 + (size_t)(q * 256) * 512 + j;
#pragma unroll 8
    for (int i = 0; i < 256; i += 2) {
      a0 = fmaf(sx[q * 256 + i],     wp[i * 512],       a0);
      a1 = fmaf(sx[q * 256 + i + 1], wp[(i + 1) * 512], a1);
    }
    part[tid] = a0 + a1;
  }
  __syncthreads();
  if (tid < 512) {
    float a = fmaxf(part[tid] + part[tid + 512] + bfc2[tid], 0.f);
    float p0 = a * Wout[tid * 2];
    float p1 = a * Wout[tid * 2 + 1];
    int ln = tid & 63, wvi = tid >> 6;
#pragma unroll
    for (int m = 1; m < 64; m <<= 1) { p0 += __shfl_xor(p0, m); p1 += __shfl_xor(p1, m); }
    if (ln == 0) { rr[wvi] = p0; rr[8 + wvi] = p1; }
  }
  __syncthreads();
  if (tid == 0) {
    float s = 0.f;
#pragma unroll
    for (int i = 0; i < 8; ++i) s += rr[i];
    out[b * 2] = s + bout[0];
  }
  if (tid == 1) {
    float s = 0.f;
#pragma unroll
    for (int i = 0; i < 8; ++i) s += rr[8 + i];
    out[b * 2 + 1] = s + bout[1];
  }
}

// ---------------------------------------------------------------------------
extern "C" void kernel_launch(void* const* d_in, const int* in_sizes, int n_in,
                              void* d_out, int out_size, void* d_ws, size_t ws_size,
                              hipStream_t stream) {
  const float* trg  = (const float*)d_in[0];
  const float* src  = (const float*)d_in[1];
  const float* Wsa  = (const float*)d_in[2];
  const float* bsa  = (const float*)d_in[3];
  const float* Wea  = (const float*)d_in[4];
  const float* bea  = (const float*)d_in[5];
  const float* lng  = (const float*)d_in[6];
  const float* lnb  = (const float*)d_in[7];
  const float* Wfc1 = (const float*)d_in[8];
  const float* bfc1 = (const float*)d_in[9];
  const float* Wfc2 = (const float*)d_in[10];
  const float* bfc2 = (const float*)d_in[11];
  const float* Wout = (const float*)d_in[12];
  const float* bout = (const float*)d_in[13];
  float* out = (float*)d_out;

  const size_t M = 32768;  // B*A
  char* ws = (char*)d_ws;
  u16* trg_h = (u16*)ws;                ws += M * 256 * 2;
  u16* src_h = (u16*)ws;                ws += M * 256 * 2;
  u16* wt     = (u16*)ws;               ws += 2048 * 256 * 2;
  u16* qkv    = (u16*)ws;               ws += M * 768 * 2;
  u16* attnb  = (u16*)ws;               ws += M * 256 * 2;
  u16* hh     = (u16*)ws;               ws += M * 256 * 2;
  u16* h2h    = (u16*)ws;               ws += M * 256 * 2;
  float* norms = (float*)ws;            ws += M * 4;
  float* pooled = (float*)ws;           ws += 64 * 256 * 4;

  u16* wt_sa_qkv = wt;
  u16* wt_sa_o   = wt + 768 * 256;
  u16* wt_ea_q   = wt + 1024 * 256;
  u16* wt_ea_kv  = wt + 1280 * 256;
  u16* wt_ea_o   = wt + 1792 * 256;
  u16* kvb = qkv + M * 256;

  prep_kernel<<<10304, 256, 0, stream>>>(trg, src, Wsa, Wea, trg_h, src_h, wt, pooled);
  // self-attention
  gemm_bias_f16<<<dim3(6, 256), 256, 0, stream>>>(trg_h, wt_sa_qkv, bsa, qkv, 768);
  attn_mfma<<<2048, 256, 0, stream>>>(qkv, 768, qkv + 256, 768, qkv + 512, 768, attnb);
  lnproj_kernel<<<512, 256, 0, stream>>>(attnb, wt_sa_o, bsa + 768, trg_h, lng, lnb,
                                         hh, nullptr);
  // cross-attention: q-proj and kv-proj fused into one dispatch
  gemm_ea_kernel<<<dim3(6, 256), 256, 0, stream>>>(hh, wt_ea_q, bea, qkv,
                                                   src_h, wt_ea_kv, bea + 256, kvb);
  attn_mfma<<<2048, 256, 0, stream>>>(qkv, 256, kvb, 512, kvb + 256, 512, attnb);
  lnproj_kernel<<<512, 256, 0, stream>>>(attnb, wt_ea_o, bea + 768, hh, lng, lnb,
                                         h2h, norms);
  // pooling (softmax fused) + FC head (split-K + ILP-2)
  poolsum_kernel<<<dim3(64, 8), 256, 0, stream>>>(norms, h2h, pooled);
  fc_kernel<<<64, 1024, 0, stream>>>(pooled, Wfc1, bfc1, Wfc2, bfc2, Wout, bout, out);

  (void)in_sizes; (void)n_in; (void)out_size; (void)ws_size;
}